// Round 17
// baseline (640.355 us; speedup 1.0000x reference)
//
#include <hip/hip_runtime.h>
#include <hip/hip_bf16.h>
#include <stdint.h>

typedef __bf16 bf16;
typedef __bf16 bf16x8 __attribute__((ext_vector_type(8)));
typedef __bf16 bf16x4 __attribute__((ext_vector_type(4)));
typedef float f32x4 __attribute__((ext_vector_type(4)));
typedef float f32x16 __attribute__((ext_vector_type(16)));

#define NB 4
#define SEQ 2048
#define DM 1024
#define NHEADS 16
#define DHEAD 64
#define MTOK (NB*SEQ)      /* 8192 */
#define NE 3072            /* 3*DM */

__device__ __forceinline__ void gl_lds16(const bf16* g, bf16* l) {
  __builtin_amdgcn_global_load_lds(
      (const __attribute__((address_space(1))) void*)g,
      (__attribute__((address_space(3))) void*)l, 16, 0, 0);
}

__device__ __forceinline__ f32x16 zero16() {
  f32x16 z;
#pragma unroll
  for (int i=0;i<16;i++) z[i]=0.f;
  return z;
}

// ---------------- convert inputs to bf16 ----------------
__global__ __launch_bounds__(256) void convert_kernel(
    const float* __restrict__ x,
    const float* __restrict__ wq, const float* __restrict__ wk,
    const float* __restrict__ wv, const float* __restrict__ wo,
    const float* __restrict__ bq, const float* __restrict__ bk,
    const float* __restrict__ bv,
    bf16* __restrict__ xb, bf16* __restrict__ wqkvb,
    bf16* __restrict__ wob, float* __restrict__ bqkv) {
  int tid = blockIdx.x*blockDim.x + threadIdx.x;
  int nt = gridDim.x*blockDim.x;
  const int NX4 = MTOK*DM/4;
  for (int i = tid; i < NX4; i += nt) {
    float4 v = ((const float4*)x)[i];
    ((bf16x4*)xb)[i] = bf16x4{(bf16)v.x,(bf16)v.y,(bf16)v.z,(bf16)v.w};
  }
  const int NW4 = DM*DM/4;
  for (int i = tid; i < NW4; i += nt) {
    float4 a = ((const float4*)wq)[i];
    ((bf16x4*)wqkvb)[i] = bf16x4{(bf16)a.x,(bf16)a.y,(bf16)a.z,(bf16)a.w};
    float4 b = ((const float4*)wk)[i];
    ((bf16x4*)wqkvb)[i+NW4] = bf16x4{(bf16)b.x,(bf16)b.y,(bf16)b.z,(bf16)b.w};
    float4 c = ((const float4*)wv)[i];
    ((bf16x4*)wqkvb)[i+2*NW4] = bf16x4{(bf16)c.x,(bf16)c.y,(bf16)c.z,(bf16)c.w};
    float4 d = ((const float4*)wo)[i];
    ((bf16x4*)wob)[i] = bf16x4{(bf16)d.x,(bf16)d.y,(bf16)d.z,(bf16)d.w};
  }
  for (int i = tid; i < DM; i += nt) {
    bqkv[i] = bq[i]; bqkv[i+DM] = bk[i]; bqkv[i+2*DM] = bv[i];
  }
}

// ---- GEMM: 128x128, BK=64, dbuf LDS, counted vmcnt(8), XOR-swizzled (R7 exact) ----
template<int OUT_MODE>
__global__ __launch_bounds__(256) void gemm_deep(
    const bf16* __restrict__ A, const bf16* __restrict__ Bm,
    const float* __restrict__ bias, void* __restrict__ Cout,
    int M, int N, int K) {
  __shared__ bf16 As[2][128*64];
  __shared__ bf16 Bs[2][128*64];
  const int bm = blockIdx.x, bn = blockIdx.y;
  const int thr = threadIdx.x;
  const int w = thr>>6, lane = thr&63;
  const int wr = w>>1, wc = w&1;
  const int l4 = lane>>4, lm = lane&15;
  f32x4 acc[4][4];
#pragma unroll
  for (int m=0;m<4;m++)
#pragma unroll
    for (int n=0;n<4;n++) acc[m][n] = f32x4{0.f,0.f,0.f,0.f};

  const bf16* Abase = A + (size_t)bm*128*K;
  const bf16* Bbase = Bm + (size_t)bn*128*K;

  const int srow = thr>>3;
  const int sch  = ((thr&7) ^ (srow&7)) * 8;
  const bf16* Ag = Abase + (size_t)srow*K + sch;
  const bf16* Bg = Bbase + (size_t)srow*K + sch;
  const int dbase = thr*8;

  const int nk = K>>6;

  int aoff[2][4], boff[2][4];
#pragma unroll
  for (int ks=0;ks<2;ks++) {
#pragma unroll
    for (int m=0;m<4;m++) {
      const int r = wr*64 + m*16 + lm;
      aoff[ks][m] = r*64 + ((((ks<<2)|l4) ^ (lm&7))*8);
    }
#pragma unroll
    for (int n=0;n<4;n++) {
      const int r = wc*64 + n*16 + lm;
      boff[ks][n] = r*64 + ((((ks<<2)|l4) ^ (lm&7))*8);
    }
  }

#pragma unroll
  for (int c=0;c<4;c++) {
    gl_lds16(Ag + (size_t)c*32*K, &As[0][c*2048 + dbase]);
    gl_lds16(Bg + (size_t)c*32*K, &Bs[0][c*2048 + dbase]);
  }

  for (int kt=0; kt<nk; ++kt) {
    const int p = kt&1;
    const int st = (kt+1 < nk) ? kt+1 : 0;
    const size_t ko = (size_t)st*64;
#pragma unroll
    for (int c=0;c<4;c++) {
      gl_lds16(Ag + ko + (size_t)c*32*K, &As[p^1][c*2048 + dbase]);
      gl_lds16(Bg + ko + (size_t)c*32*K, &Bs[p^1][c*2048 + dbase]);
    }
    asm volatile("s_waitcnt vmcnt(8)" ::: "memory");
    __builtin_amdgcn_s_barrier();
    __builtin_amdgcn_sched_barrier(0);

    const bf16* Ac = As[p];
    const bf16* Bc = Bs[p];
    __builtin_amdgcn_s_setprio(1);
#pragma unroll
    for (int ks=0;ks<2;ks++) {
      bf16x8 af[4], bfr[4];
#pragma unroll
      for (int m=0;m<4;m++) af[m] = *(const bf16x8*)&Ac[aoff[ks][m]];
#pragma unroll
      for (int n=0;n<4;n++) bfr[n] = *(const bf16x8*)&Bc[boff[ks][n]];
#pragma unroll
      for (int m=0;m<4;m++)
#pragma unroll
        for (int n=0;n<4;n++)
          acc[m][n] = __builtin_amdgcn_mfma_f32_16x16x32_bf16(af[m], bfr[n], acc[m][n], 0, 0, 0);
    }
    __builtin_amdgcn_s_setprio(0);
    __builtin_amdgcn_s_barrier();
    __builtin_amdgcn_sched_barrier(0);
  }

  const int rbase = bm*128 + wr*64 + l4*4;
  const int cbase = bn*128 + wc*64;
#pragma unroll
  for (int n=0;n<4;n++) {
    const int col = cbase + n*16 + lm;
    const float bv = bias[col];
#pragma unroll
    for (int m=0;m<4;m++) {
#pragma unroll
      for (int j=0;j<4;j++) {
        const int row = rbase + m*16 + j;
        const float v = acc[m][n][j] + bv;
        if (OUT_MODE == 0) ((bf16*)Cout)[(size_t)row*N + col] = (bf16)v;
        else               ((float*)Cout)[(size_t)row*N + col] = v;
      }
    }
  }
}

// ---------------- transpose V: qkv[b,s, 2048+h*64+d] -> vt[b,h,d,s] ----------------
__global__ __launch_bounds__(256) void transpose_v(const bf16* __restrict__ qkv,
                                                   bf16* __restrict__ vt) {
  __shared__ bf16 tile[64*72];
  const int s0 = blockIdx.x*64;
  const int bh = blockIdx.y;
  const bf16* src = qkv + (size_t)((bh>>4)*SEQ + s0)*NE + 2*DM + (bh&15)*64;
  const int thr = threadIdx.x;
#pragma unroll
  for (int i=0;i<2;i++) {
    int idx = thr + i*256;
    int row = idx>>3, part = idx&7;
    *(bf16x8*)&tile[row*72 + part*8] = *(const bf16x8*)(src + (size_t)row*NE + part*8);
  }
  __syncthreads();
  bf16* dst = vt + (size_t)bh*64*SEQ + s0;
#pragma unroll
  for (int i=0;i<2;i++) {
    int idx = thr + i*256;
    int d = idx>>3, part = idx&7;
    bf16x8 v;
#pragma unroll
    for (int j=0;j<8;j++) v[j] = tile[(part*8+j)*72 + d];
    *(bf16x8*)(dst + (size_t)d*SEQ + part*8) = v;
  }
}

// ---------------- flash attention: KV-split, 4 blocks/CU ----------------
// grid: (SEQ/256, NB*NHEADS, 2), block 256. Fixed-max softmax => partials add
// exactly. Writes unnormalized bf16 O-partials + PER-HEAD f32 l-partials
// (lp indexed [kvh][token][h] — R16's bug was missing the head dim).
__global__ __launch_bounds__(256, 4) void attn_kernel(
    const bf16* __restrict__ qkv, const bf16* __restrict__ vt,
    bf16* __restrict__ po, float* __restrict__ lp,
    const float* __restrict__ temperature) {
  __shared__ bf16 smem[4][64*64];   // [K0][K1][V0][V1], rows 128B, XOR-swizzled 16B chunks
  const int bh = blockIdx.y;
  const int kvh = blockIdx.z;
  const int b = bh>>4, h = bh&15;
  const int thr = threadIdx.x;
  const int w = thr>>6, lane = thr&63;
  const int l31 = lane&31, hi = lane>>5;
  const float sc2 = 1.4426950408889634f / (8.0f * temperature[0]);
  const int q0 = blockIdx.x*256 + w*64;
  const int NT = SEQ/64/2;          // 16 tiles per block (half the KV range)
#define KBUFB 8192        /* bytes per buffer */
#define VOFFB 16384       /* V region byte offset */

  // Q fragments for both q-halves, pre-scaled by sc2
  bf16x8 qfA[4], qfB[4];
  {
    const bf16* qpA = qkv + (size_t)(b*SEQ + q0 + l31)*NE + h*64 + hi*8;
    const bf16* qpB = qpA + (size_t)32*NE;
#pragma unroll
    for (int s=0;s<4;s++) {
      bf16x8 qa = *(const bf16x8*)(qpA + s*16);
      bf16x8 qb = *(const bf16x8*)(qpB + s*16);
#pragma unroll
      for (int j=0;j<8;j++) {
        qfA[s][j] = (bf16)((float)qa[j] * sc2);
        qfB[s][j] = (bf16)((float)qb[j] * sc2);
      }
    }
  }

  f32x16 oA0 = zero16(), oA1 = zero16();
  f32x16 oB0 = zero16(), oB1 = zero16();
  float lpA = 0.f, lpB = 0.f;

  const bf16* Kbase = qkv + (size_t)b*SEQ*NE + DM + h*64 + (size_t)(kvh*1024)*NE;
  const bf16* Vbase = vt + (size_t)bh*64*SEQ + kvh*1024;

  // staging: thread -> row sr (0..63), chunk scb (0..3); swizzle chunk^=(row&7)
  const int sr = thr>>2, scb = thr&3;
  const int wb0 = sr*128 + (((scb*2+0) ^ (sr&7))<<4);
  const int wb1 = sr*128 + (((scb*2+1) ^ (sr&7))<<4);
  const int rsw = l31&7;

  // precomputed fragment read addresses; buffer/V region via imm offsets
  const char* kr0[4];
  const char* kr1[4];
#pragma unroll
  for (int s=0;s<4;s++) {
    const int slot = s*2 + hi;
    kr0[s] = (const char*)smem + l31*128      + ((slot ^ rsw)<<4);
    kr1[s] = (const char*)smem + (32+l31)*128 + ((slot ^ rsw)<<4);
  }

  const bf16* kgb = Kbase + (size_t)sr*NE + scb*16;
  const bf16* vgb = Vbase + (size_t)sr*SEQ + scb*16;

  bf16x8 ka, kb, va, vb;
  ka = *(const bf16x8*)(kgb);
  kb = *(const bf16x8*)(kgb + 8);
  va = *(const bf16x8*)(vgb);
  vb = *(const bf16x8*)(vgb + 8);
  *(bf16x8*)((char*)smem + wb0)         = ka;
  *(bf16x8*)((char*)smem + wb1)         = kb;
  *(bf16x8*)((char*)smem + VOFFB + wb0) = va;
  *(bf16x8*)((char*)smem + VOFFB + wb1) = vb;
  kgb += (size_t)64*NE; vgb += 64;
  ka = *(const bf16x8*)(kgb);
  kb = *(const bf16x8*)(kgb + 8);
  va = *(const bf16x8*)(vgb);
  vb = *(const bf16x8*)(vgb + 8);
  kgb += (size_t)64*NE; vgb += 64;
  __syncthreads();

#define MAKE_PU(PU, S0, S1, KS)                                                \
  { float e0,e1,e2,e3,e4,e5,e6,e7;                                             \
    if ((KS)==0)      { e0=S0[0]; e1=S0[1]; e2=S0[2]; e3=S0[3];                \
                        e4=S0[4]; e5=S0[5]; e6=S0[6]; e7=S0[7]; }              \
    else if ((KS)==1) { e0=S0[8]; e1=S0[9]; e2=S0[10];e3=S0[11];               \
                        e4=S0[12];e5=S0[13];e6=S0[14];e7=S0[15]; }             \
    else if ((KS)==2) { e0=S1[0]; e1=S1[1]; e2=S1[2]; e3=S1[3];                \
                        e4=S1[4]; e5=S1[5]; e6=S1[6]; e7=S1[7]; }              \
    else              { e0=S1[8]; e1=S1[9]; e2=S1[10];e3=S1[11];               \
                        e4=S1[12];e5=S1[13];e6=S1[14];e7=S1[15]; }             \
    unsigned a0,a1,b0,b1;                                                      \
    asm("v_cvt_pk_bf16_f32 %0, %1, %2" : "=v"(a0) : "v"(e0), "v"(e1));         \
    asm("v_cvt_pk_bf16_f32 %0, %1, %2" : "=v"(a1) : "v"(e2), "v"(e3));         \
    asm("v_cvt_pk_bf16_f32 %0, %1, %2" : "=v"(b0) : "v"(e4), "v"(e5));         \
    asm("v_cvt_pk_bf16_f32 %0, %1, %2" : "=v"(b1) : "v"(e6), "v"(e7));         \
    asm("v_permlane32_swap_b32 %0, %1" : "+v"(a0), "+v"(b0));                  \
    asm("v_permlane32_swap_b32 %0, %1" : "+v"(a1), "+v"(b1));                  \
    PU.u[0]=a0; PU.u[1]=a1; PU.u[2]=b0; PU.u[3]=b1; }

#define ATTN_TILE(P, T)                                                        \
  {                                                                            \
    const int t_ = (T);                                                        \
    if (t_ < NT-1) {                                                           \
      *(bf16x8*)((char*)smem + ((P)^1)*KBUFB + wb0)         = ka;              \
      *(bf16x8*)((char*)smem + ((P)^1)*KBUFB + wb1)         = kb;              \
      *(bf16x8*)((char*)smem + VOFFB + ((P)^1)*KBUFB + wb0) = va;              \
      *(bf16x8*)((char*)smem + VOFFB + ((P)^1)*KBUFB + wb1) = vb;              \
      if (t_ < NT-2) {                                                         \
        ka = *(const bf16x8*)(kgb);                                            \
        kb = *(const bf16x8*)(kgb + 8);                                        \
        va = *(const bf16x8*)(vgb);                                            \
        vb = *(const bf16x8*)(vgb + 8);                                        \
        kgb += (size_t)64*NE; vgb += 64;                                       \
      }                                                                        \
    }                                                                          \
    f32x16 sA0 = zero16(), sA1 = zero16(), sB0 = zero16(), sB1 = zero16();     \
    __builtin_amdgcn_s_setprio(1);                                             \
    _Pragma("unroll")                                                          \
    for (int s=0;s<4;s++) {                                                    \
      bf16x8 kf0 = *(const bf16x8*)(kr0[s] + (P)*KBUFB);                       \
      bf16x8 kf1 = *(const bf16x8*)(kr1[s] + (P)*KBUFB);                       \
      sA0 = __builtin_amdgcn_mfma_f32_32x32x16_bf16(kf0, qfA[s], sA0, 0,0,0);  \
      sB0 = __builtin_amdgcn_mfma_f32_32x32x16_bf16(kf0, qfB[s], sB0, 0,0,0);  \
      sA1 = __builtin_amdgcn_mfma_f32_32x32x16_bf16(kf1, qfA[s], sA1, 0,0,0);  \
      sB1 = __builtin_amdgcn_mfma_f32_32x32x16_bf16(kf1, qfB[s], sB1, 0,0,0);  \
    }                                                                          \
    __builtin_amdgcn_s_setprio(0);                                             \
    _Pragma("unroll")                                                          \
    for (int r=0;r<16;r++) { sA0[r] = __builtin_amdgcn_exp2f(sA0[r]); lpA += sA0[r]; } \
    _Pragma("unroll")                                                          \
    for (int r=0;r<16;r++) { sA1[r] = __builtin_amdgcn_exp2f(sA1[r]); lpA += sA1[r]; } \
    _Pragma("unroll")                                                          \
    for (int r=0;r<16;r++) { sB0[r] = __builtin_amdgcn_exp2f(sB0[r]); lpB += sB0[r]; } \
    _Pragma("unroll")                                                          \
    for (int r=0;r<16;r++) { sB1[r] = __builtin_amdgcn_exp2f(sB1[r]); lpB += sB1[r]; } \
    __builtin_amdgcn_s_setprio(1);                                             \
    _Pragma("unroll")                                                          \
    for (int ks=0;ks<4;ks++) {                                                 \
      union { unsigned u[4]; bf16x8 v; } puA, puB;                             \
      MAKE_PU(puA, sA0, sA1, ks);                                              \
      MAKE_PU(puB, sB0, sB1, ks);                                              \
      bf16x8 vf0, vf1;                                                         \
      if (ks==0) { vf0 = *(const bf16x8*)(kr0[0] + VOFFB + (P)*KBUFB);         \
                   vf1 = *(const bf16x8*)(kr1[0] + VOFFB + (P)*KBUFB); }       \
      else if (ks==1) { vf0 = *(const bf16x8*)(kr0[1] + VOFFB + (P)*KBUFB);    \
                   vf1 = *(const bf16x8*)(kr1[1] + VOFFB + (P)*KBUFB); }       \
      else if (ks==2) { vf0 = *(const bf16x8*)(kr0[2] + VOFFB + (P)*KBUFB);    \
                   vf1 = *(const bf16x8*)(kr1[2] + VOFFB + (P)*KBUFB); }       \
      else { vf0 = *(const bf16x8*)(kr0[3] + VOFFB + (P)*KBUFB);               \
             vf1 = *(const bf16x8*)(kr1[3] + VOFFB + (P)*KBUFB); }             \
      oA0 = __builtin_amdgcn_mfma_f32_32x32x16_bf16(puA.v, vf0, oA0, 0,0,0);   \
      oA1 = __builtin_amdgcn_mfma_f32_32x32x16_bf16(puA.v, vf1, oA1, 0,0,0);   \
      oB0 = __builtin_amdgcn_mfma_f32_32x32x16_bf16(puB.v, vf0, oB0, 0,0,0);   \
      oB1 = __builtin_amdgcn_mfma_f32_32x32x16_bf16(puB.v, vf1, oB1, 0,0,0);   \
    }                                                                          \
    __builtin_amdgcn_s_setprio(0);                                             \
    __syncthreads();                                                           \
  }

  for (int t2=0; t2<NT/2; ++t2) {
    ATTN_TILE(0, 2*t2);
    ATTN_TILE(1, 2*t2+1);
  }
#undef ATTN_TILE
#undef MAKE_PU

  // combine hi-halves of the rowsum; write UNNORMALIZED partials
  lpA += __shfl_xor(lpA, 32);
  lpB += __shfl_xor(lpB, 32);
  bf16* pob = po + (size_t)kvh*MTOK*DM;
#pragma unroll
  for (int r=0;r<16;r++) {
    const int qi = (r&3) + 8*(r>>2) + hi*4;
    {
      bf16* op = pob + (size_t)(b*SEQ + q0 + qi)*DM + h*64 + l31;
      op[0]  = (bf16)oA0[r];
      op[32] = (bf16)oA1[r];
    }
    {
      bf16* op = pob + (size_t)(b*SEQ + q0 + 32 + qi)*DM + h*64 + l31;
      op[0]  = (bf16)oB0[r];
      op[32] = (bf16)oB1[r];
    }
  }
  if (hi == 0) {
    lp[((size_t)kvh*MTOK + b*SEQ + q0 + l31)*NHEADS + h]      = lpA;
    lp[((size_t)kvh*MTOK + b*SEQ + q0 + 32 + l31)*NHEADS + h] = lpB;
  }
}

// ---------------- combine: aout = (po0+po1) * qs / (lp0+lp1) ----------------
__global__ __launch_bounds__(256) void combine_kernel(
    const bf16* __restrict__ po, const float* __restrict__ lp,
    const float* __restrict__ q_scale, bf16* __restrict__ aout) {
  const int idx = blockIdx.x*256 + threadIdx.x;     // over MTOK * DM/8
  const int token = idx >> 7;                       // DM/8 = 128
  const int d8 = idx & 127;
  const int d0 = d8 * 8;
  const int h = d8 >> 3;
  bf16x8 a = *(const bf16x8*)(po + (size_t)token*DM + d0);
  bf16x8 b = *(const bf16x8*)(po + (size_t)MTOK*DM + (size_t)token*DM + d0);
  const float l = lp[(size_t)token*NHEADS + h] + lp[((size_t)MTOK + token)*NHEADS + h];
  const float iv = q_scale[h] / l;
  bf16x8 o;
#pragma unroll
  for (int j=0;j<8;j++) o[j] = (bf16)(((float)a[j] + (float)b[j]) * iv);
  *(bf16x8*)(aout + (size_t)token*DM + d0) = o;
}

// ---------------- launch ----------------
extern "C" void kernel_launch(void* const* d_in, const int* in_sizes, int n_in,
                              void* d_out, int out_size, void* d_ws, size_t ws_size,
                              hipStream_t stream) {
  (void)in_sizes; (void)n_in; (void)out_size; (void)ws_size;
  const float* x  = (const float*)d_in[0];
  const float* wq = (const float*)d_in[1];
  const float* bq = (const float*)d_in[2];
  const float* wk = (const float*)d_in[3];
  const float* bk = (const float*)d_in[4];
  const float* wv = (const float*)d_in[5];
  const float* bv = (const float*)d_in[6];
  const float* wo = (const float*)d_in[7];
  const float* bo = (const float*)d_in[8];
  const float* temp = (const float*)d_in[9];
  const float* qsc  = (const float*)d_in[10];

  char* ws = (char*)d_ws;
  bf16* xb    = (bf16*)ws; ws += (size_t)MTOK*DM*2;
  bf16* wqkvb = (bf16*)ws; ws += (size_t)NE*DM*2;
  bf16* wob   = (bf16*)ws; ws += (size_t)DM*DM*2;
  float* bqkv = (float*)ws; ws += (size_t)NE*4;
  bf16* qkv   = (bf16*)ws; ws += (size_t)MTOK*NE*2;
  bf16* vt    = (bf16*)ws; ws += (size_t)NB*NHEADS*DHEAD*SEQ*2;
  bf16* aout  = (bf16*)ws; ws += (size_t)MTOK*DM*2;
  bf16* po    = (bf16*)ws; ws += (size_t)2*MTOK*DM*2;
  float* lp   = (float*)ws; ws += (size_t)2*MTOK*NHEADS*4;

  convert_kernel<<<dim3(1024), dim3(256), 0, stream>>>(x, wq, wk, wv, wo, bq, bk, bv,
                                                       xb, wqkvb, wob, bqkv);
  gemm_deep<0><<<dim3(MTOK/128, NE/128), dim3(256), 0, stream>>>(xb, wqkvb, bqkv, qkv,
                                                                 MTOK, NE, DM);
  transpose_v<<<dim3(SEQ/64, NB*NHEADS), dim3(256), 0, stream>>>(qkv, vt);
  attn_kernel<<<dim3(SEQ/256, NB*NHEADS, 2), dim3(256), 0, stream>>>(qkv, vt, po, lp, temp);
  combine_kernel<<<dim3(MTOK*DM/8/256), dim3(256), 0, stream>>>(po, lp, qsc, aout);
  gemm_deep<1><<<dim3(MTOK/128, DM/128), dim3(256), 0, stream>>>(aout, wob, bo, d_out,
                                                                 MTOK, DM, DM);
}

// Round 18
// 192.096 us; speedup vs baseline: 3.3335x; 3.3335x over previous
//
#include <hip/hip_runtime.h>
#include <hip/hip_bf16.h>
#include <stdint.h>

typedef __bf16 bf16;
typedef __bf16 bf16x8 __attribute__((ext_vector_type(8)));
typedef __bf16 bf16x4 __attribute__((ext_vector_type(4)));
typedef float f32x4 __attribute__((ext_vector_type(4)));
typedef float f32x16 __attribute__((ext_vector_type(16)));

#define NB 4
#define SEQ 2048
#define DM 1024
#define NHEADS 16
#define DHEAD 64
#define MTOK (NB*SEQ)      /* 8192 */
#define NE 3072            /* 3*DM */

__device__ __forceinline__ void gl_lds16(const bf16* g, bf16* l) {
  __builtin_amdgcn_global_load_lds(
      (const __attribute__((address_space(1))) void*)g,
      (__attribute__((address_space(3))) void*)l, 16, 0, 0);
}

__device__ __forceinline__ f32x16 zero16() {
  f32x16 z;
#pragma unroll
  for (int i=0;i<16;i++) z[i]=0.f;
  return z;
}

// ---------------- convert inputs to bf16 ----------------
__global__ __launch_bounds__(256) void convert_kernel(
    const float* __restrict__ x,
    const float* __restrict__ wq, const float* __restrict__ wk,
    const float* __restrict__ wv, const float* __restrict__ wo,
    const float* __restrict__ bq, const float* __restrict__ bk,
    const float* __restrict__ bv,
    bf16* __restrict__ xb, bf16* __restrict__ wqkvb,
    bf16* __restrict__ wob, float* __restrict__ bqkv) {
  int tid = blockIdx.x*blockDim.x + threadIdx.x;
  int nt = gridDim.x*blockDim.x;
  const int NX4 = MTOK*DM/4;
  for (int i = tid; i < NX4; i += nt) {
    float4 v = ((const float4*)x)[i];
    ((bf16x4*)xb)[i] = bf16x4{(bf16)v.x,(bf16)v.y,(bf16)v.z,(bf16)v.w};
  }
  const int NW4 = DM*DM/4;
  for (int i = tid; i < NW4; i += nt) {
    float4 a = ((const float4*)wq)[i];
    ((bf16x4*)wqkvb)[i] = bf16x4{(bf16)a.x,(bf16)a.y,(bf16)a.z,(bf16)a.w};
    float4 b = ((const float4*)wk)[i];
    ((bf16x4*)wqkvb)[i+NW4] = bf16x4{(bf16)b.x,(bf16)b.y,(bf16)b.z,(bf16)b.w};
    float4 c = ((const float4*)wv)[i];
    ((bf16x4*)wqkvb)[i+2*NW4] = bf16x4{(bf16)c.x,(bf16)c.y,(bf16)c.z,(bf16)c.w};
    float4 d = ((const float4*)wo)[i];
    ((bf16x4*)wob)[i] = bf16x4{(bf16)d.x,(bf16)d.y,(bf16)d.z,(bf16)d.w};
  }
  for (int i = tid; i < DM; i += nt) {
    bqkv[i] = bq[i]; bqkv[i+DM] = bk[i]; bqkv[i+2*DM] = bv[i];
  }
}

// ---- GEMM: 128x128, BK=64, dbuf LDS, counted vmcnt(8), XOR-swizzled (R7 exact) ----
template<int OUT_MODE>
__global__ __launch_bounds__(256) void gemm_deep(
    const bf16* __restrict__ A, const bf16* __restrict__ Bm,
    const float* __restrict__ bias, void* __restrict__ Cout,
    int M, int N, int K) {
  __shared__ bf16 As[2][128*64];
  __shared__ bf16 Bs[2][128*64];
  const int bm = blockIdx.x, bn = blockIdx.y;
  const int thr = threadIdx.x;
  const int w = thr>>6, lane = thr&63;
  const int wr = w>>1, wc = w&1;
  const int l4 = lane>>4, lm = lane&15;
  f32x4 acc[4][4];
#pragma unroll
  for (int m=0;m<4;m++)
#pragma unroll
    for (int n=0;n<4;n++) acc[m][n] = f32x4{0.f,0.f,0.f,0.f};

  const bf16* Abase = A + (size_t)bm*128*K;
  const bf16* Bbase = Bm + (size_t)bn*128*K;

  const int srow = thr>>3;
  const int sch  = ((thr&7) ^ (srow&7)) * 8;
  const bf16* Ag = Abase + (size_t)srow*K + sch;
  const bf16* Bg = Bbase + (size_t)srow*K + sch;
  const int dbase = thr*8;

  const int nk = K>>6;

  int aoff[2][4], boff[2][4];
#pragma unroll
  for (int ks=0;ks<2;ks++) {
#pragma unroll
    for (int m=0;m<4;m++) {
      const int r = wr*64 + m*16 + lm;
      aoff[ks][m] = r*64 + ((((ks<<2)|l4) ^ (lm&7))*8);
    }
#pragma unroll
    for (int n=0;n<4;n++) {
      const int r = wc*64 + n*16 + lm;
      boff[ks][n] = r*64 + ((((ks<<2)|l4) ^ (lm&7))*8);
    }
  }

#pragma unroll
  for (int c=0;c<4;c++) {
    gl_lds16(Ag + (size_t)c*32*K, &As[0][c*2048 + dbase]);
    gl_lds16(Bg + (size_t)c*32*K, &Bs[0][c*2048 + dbase]);
  }

  for (int kt=0; kt<nk; ++kt) {
    const int p = kt&1;
    const int st = (kt+1 < nk) ? kt+1 : 0;
    const size_t ko = (size_t)st*64;
#pragma unroll
    for (int c=0;c<4;c++) {
      gl_lds16(Ag + ko + (size_t)c*32*K, &As[p^1][c*2048 + dbase]);
      gl_lds16(Bg + ko + (size_t)c*32*K, &Bs[p^1][c*2048 + dbase]);
    }
    asm volatile("s_waitcnt vmcnt(8)" ::: "memory");
    __builtin_amdgcn_s_barrier();
    __builtin_amdgcn_sched_barrier(0);

    const bf16* Ac = As[p];
    const bf16* Bc = Bs[p];
    __builtin_amdgcn_s_setprio(1);
#pragma unroll
    for (int ks=0;ks<2;ks++) {
      bf16x8 af[4], bfr[4];
#pragma unroll
      for (int m=0;m<4;m++) af[m] = *(const bf16x8*)&Ac[aoff[ks][m]];
#pragma unroll
      for (int n=0;n<4;n++) bfr[n] = *(const bf16x8*)&Bc[boff[ks][n]];
#pragma unroll
      for (int m=0;m<4;m++)
#pragma unroll
        for (int n=0;n<4;n++)
          acc[m][n] = __builtin_amdgcn_mfma_f32_16x16x32_bf16(af[m], bfr[n], acc[m][n], 0, 0, 0);
    }
    __builtin_amdgcn_s_setprio(0);
    __builtin_amdgcn_s_barrier();
    __builtin_amdgcn_sched_barrier(0);
  }

  const int rbase = bm*128 + wr*64 + l4*4;
  const int cbase = bn*128 + wc*64;
#pragma unroll
  for (int n=0;n<4;n++) {
    const int col = cbase + n*16 + lm;
    const float bv = bias[col];
#pragma unroll
    for (int m=0;m<4;m++) {
#pragma unroll
      for (int j=0;j<4;j++) {
        const int row = rbase + m*16 + j;
        const float v = acc[m][n][j] + bv;
        if (OUT_MODE == 0) ((bf16*)Cout)[(size_t)row*N + col] = (bf16)v;
        else               ((float*)Cout)[(size_t)row*N + col] = v;
      }
    }
  }
}

// ---------------- transpose V: qkv[b,s, 2048+h*64+d] -> vt[b,h,d,s] ----------------
__global__ __launch_bounds__(256) void transpose_v(const bf16* __restrict__ qkv,
                                                   bf16* __restrict__ vt) {
  __shared__ bf16 tile[64*72];
  const int s0 = blockIdx.x*64;
  const int bh = blockIdx.y;
  const bf16* src = qkv + (size_t)((bh>>4)*SEQ + s0)*NE + 2*DM + (bh&15)*64;
  const int thr = threadIdx.x;
#pragma unroll
  for (int i=0;i<2;i++) {
    int idx = thr + i*256;
    int row = idx>>3, part = idx&7;
    *(bf16x8*)&tile[row*72 + part*8] = *(const bf16x8*)(src + (size_t)row*NE + part*8);
  }
  __syncthreads();
  bf16* dst = vt + (size_t)bh*64*SEQ + s0;
#pragma unroll
  for (int i=0;i<2;i++) {
    int idx = thr + i*256;
    int d = idx>>3, part = idx&7;
    bf16x8 v;
#pragma unroll
    for (int j=0;j<8;j++) v[j] = tile[(part*8+j)*72 + d];
    *(bf16x8*)(dst + (size_t)d*SEQ + part*8) = v;
  }
}

// ---------------- flash attention: KV-split ----------------
// grid: (SEQ/256, NB*NHEADS, 2), block 256, launch_bounds (256,2): compiler
// allocates ~112 VGPR (R15-measured) -> 4 blocks/CU reached NATURALLY
// (512/112 -> 4 waves/SIMD; LDS 32KB x4 = 128 <= 160KB). R17's (256,4) bound
// strangled the allocator to 64 VGPR -> accumulator spill -> 1.3GB scratch traffic.
// Fixed-max softmax => partials add exactly; unnormalized bf16 O + per-head f32 l.
__global__ __launch_bounds__(256, 2) void attn_kernel(
    const bf16* __restrict__ qkv, const bf16* __restrict__ vt,
    bf16* __restrict__ po, float* __restrict__ lp,
    const float* __restrict__ temperature) {
  __shared__ bf16 smem[4][64*64];   // [K0][K1][V0][V1], rows 128B, XOR-swizzled 16B chunks
  const int bh = blockIdx.y;
  const int kvh = blockIdx.z;
  const int b = bh>>4, h = bh&15;
  const int thr = threadIdx.x;
  const int w = thr>>6, lane = thr&63;
  const int l31 = lane&31, hi = lane>>5;
  const float sc2 = 1.4426950408889634f / (8.0f * temperature[0]);
  const int q0 = blockIdx.x*256 + w*64;
  const int NT = SEQ/64/2;          // 16 tiles per block (half the KV range)
#define KBUFB 8192        /* bytes per buffer */
#define VOFFB 16384       /* V region byte offset */

  // Q fragments for both q-halves, pre-scaled by sc2
  bf16x8 qfA[4], qfB[4];
  {
    const bf16* qpA = qkv + (size_t)(b*SEQ + q0 + l31)*NE + h*64 + hi*8;
    const bf16* qpB = qpA + (size_t)32*NE;
#pragma unroll
    for (int s=0;s<4;s++) {
      bf16x8 qa = *(const bf16x8*)(qpA + s*16);
      bf16x8 qb = *(const bf16x8*)(qpB + s*16);
#pragma unroll
      for (int j=0;j<8;j++) {
        qfA[s][j] = (bf16)((float)qa[j] * sc2);
        qfB[s][j] = (bf16)((float)qb[j] * sc2);
      }
    }
  }

  f32x16 oA0 = zero16(), oA1 = zero16();
  f32x16 oB0 = zero16(), oB1 = zero16();
  float lpA = 0.f, lpB = 0.f;

  const bf16* Kbase = qkv + (size_t)b*SEQ*NE + DM + h*64 + (size_t)(kvh*1024)*NE;
  const bf16* Vbase = vt + (size_t)bh*64*SEQ + kvh*1024;

  // staging: thread -> row sr (0..63), chunk scb (0..3); swizzle chunk^=(row&7)
  const int sr = thr>>2, scb = thr&3;
  const int wb0 = sr*128 + (((scb*2+0) ^ (sr&7))<<4);
  const int wb1 = sr*128 + (((scb*2+1) ^ (sr&7))<<4);
  const int rsw = l31&7;

  // precomputed fragment read addresses; buffer/V region via imm offsets
  const char* kr0[4];
  const char* kr1[4];
#pragma unroll
  for (int s=0;s<4;s++) {
    const int slot = s*2 + hi;
    kr0[s] = (const char*)smem + l31*128      + ((slot ^ rsw)<<4);
    kr1[s] = (const char*)smem + (32+l31)*128 + ((slot ^ rsw)<<4);
  }

  const bf16* kgb = Kbase + (size_t)sr*NE + scb*16;
  const bf16* vgb = Vbase + (size_t)sr*SEQ + scb*16;

  bf16x8 ka, kb, va, vb;
  ka = *(const bf16x8*)(kgb);
  kb = *(const bf16x8*)(kgb + 8);
  va = *(const bf16x8*)(vgb);
  vb = *(const bf16x8*)(vgb + 8);
  *(bf16x8*)((char*)smem + wb0)         = ka;
  *(bf16x8*)((char*)smem + wb1)         = kb;
  *(bf16x8*)((char*)smem + VOFFB + wb0) = va;
  *(bf16x8*)((char*)smem + VOFFB + wb1) = vb;
  kgb += (size_t)64*NE; vgb += 64;
  ka = *(const bf16x8*)(kgb);
  kb = *(const bf16x8*)(kgb + 8);
  va = *(const bf16x8*)(vgb);
  vb = *(const bf16x8*)(vgb + 8);
  kgb += (size_t)64*NE; vgb += 64;
  __syncthreads();

#define MAKE_PU(PU, S0, S1, KS)                                                \
  { float e0,e1,e2,e3,e4,e5,e6,e7;                                             \
    if ((KS)==0)      { e0=S0[0]; e1=S0[1]; e2=S0[2]; e3=S0[3];                \
                        e4=S0[4]; e5=S0[5]; e6=S0[6]; e7=S0[7]; }              \
    else if ((KS)==1) { e0=S0[8]; e1=S0[9]; e2=S0[10];e3=S0[11];               \
                        e4=S0[12];e5=S0[13];e6=S0[14];e7=S0[15]; }             \
    else if ((KS)==2) { e0=S1[0]; e1=S1[1]; e2=S1[2]; e3=S1[3];                \
                        e4=S1[4]; e5=S1[5]; e6=S1[6]; e7=S1[7]; }              \
    else              { e0=S1[8]; e1=S1[9]; e2=S1[10];e3=S1[11];               \
                        e4=S1[12];e5=S1[13];e6=S1[14];e7=S1[15]; }             \
    unsigned a0,a1,b0,b1;                                                      \
    asm("v_cvt_pk_bf16_f32 %0, %1, %2" : "=v"(a0) : "v"(e0), "v"(e1));         \
    asm("v_cvt_pk_bf16_f32 %0, %1, %2" : "=v"(a1) : "v"(e2), "v"(e3));         \
    asm("v_cvt_pk_bf16_f32 %0, %1, %2" : "=v"(b0) : "v"(e4), "v"(e5));         \
    asm("v_cvt_pk_bf16_f32 %0, %1, %2" : "=v"(b1) : "v"(e6), "v"(e7));         \
    asm("v_permlane32_swap_b32 %0, %1" : "+v"(a0), "+v"(b0));                  \
    asm("v_permlane32_swap_b32 %0, %1" : "+v"(a1), "+v"(b1));                  \
    PU.u[0]=a0; PU.u[1]=a1; PU.u[2]=b0; PU.u[3]=b1; }

#define ATTN_TILE(P, T)                                                        \
  {                                                                            \
    const int t_ = (T);                                                        \
    if (t_ < NT-1) {                                                           \
      *(bf16x8*)((char*)smem + ((P)^1)*KBUFB + wb0)         = ka;              \
      *(bf16x8*)((char*)smem + ((P)^1)*KBUFB + wb1)         = kb;              \
      *(bf16x8*)((char*)smem + VOFFB + ((P)^1)*KBUFB + wb0) = va;              \
      *(bf16x8*)((char*)smem + VOFFB + ((P)^1)*KBUFB + wb1) = vb;              \
      if (t_ < NT-2) {                                                         \
        ka = *(const bf16x8*)(kgb);                                            \
        kb = *(const bf16x8*)(kgb + 8);                                        \
        va = *(const bf16x8*)(vgb);                                            \
        vb = *(const bf16x8*)(vgb + 8);                                        \
        kgb += (size_t)64*NE; vgb += 64;                                       \
      }                                                                        \
    }                                                                          \
    f32x16 sA0 = zero16(), sA1 = zero16(), sB0 = zero16(), sB1 = zero16();     \
    __builtin_amdgcn_s_setprio(1);                                             \
    _Pragma("unroll")                                                          \
    for (int s=0;s<4;s++) {                                                    \
      bf16x8 kf0 = *(const bf16x8*)(kr0[s] + (P)*KBUFB);                       \
      bf16x8 kf1 = *(const bf16x8*)(kr1[s] + (P)*KBUFB);                       \
      sA0 = __builtin_amdgcn_mfma_f32_32x32x16_bf16(kf0, qfA[s], sA0, 0,0,0);  \
      sB0 = __builtin_amdgcn_mfma_f32_32x32x16_bf16(kf0, qfB[s], sB0, 0,0,0);  \
      sA1 = __builtin_amdgcn_mfma_f32_32x32x16_bf16(kf1, qfA[s], sA1, 0,0,0);  \
      sB1 = __builtin_amdgcn_mfma_f32_32x32x16_bf16(kf1, qfB[s], sB1, 0,0,0);  \
    }                                                                          \
    __builtin_amdgcn_s_setprio(0);                                             \
    _Pragma("unroll")                                                          \
    for (int r=0;r<16;r++) { sA0[r] = __builtin_amdgcn_exp2f(sA0[r]); lpA += sA0[r]; } \
    _Pragma("unroll")                                                          \
    for (int r=0;r<16;r++) { sA1[r] = __builtin_amdgcn_exp2f(sA1[r]); lpA += sA1[r]; } \
    _Pragma("unroll")                                                          \
    for (int r=0;r<16;r++) { sB0[r] = __builtin_amdgcn_exp2f(sB0[r]); lpB += sB0[r]; } \
    _Pragma("unroll")                                                          \
    for (int r=0;r<16;r++) { sB1[r] = __builtin_amdgcn_exp2f(sB1[r]); lpB += sB1[r]; } \
    __builtin_amdgcn_s_setprio(1);                                             \
    _Pragma("unroll")                                                          \
    for (int ks=0;ks<4;ks++) {                                                 \
      union { unsigned u[4]; bf16x8 v; } puA, puB;                             \
      MAKE_PU(puA, sA0, sA1, ks);                                              \
      MAKE_PU(puB, sB0, sB1, ks);                                              \
      bf16x8 vf0, vf1;                                                         \
      if (ks==0) { vf0 = *(const bf16x8*)(kr0[0] + VOFFB + (P)*KBUFB);         \
                   vf1 = *(const bf16x8*)(kr1[0] + VOFFB + (P)*KBUFB); }       \
      else if (ks==1) { vf0 = *(const bf16x8*)(kr0[1] + VOFFB + (P)*KBUFB);    \
                   vf1 = *(const bf16x8*)(kr1[1] + VOFFB + (P)*KBUFB); }       \
      else if (ks==2) { vf0 = *(const bf16x8*)(kr0[2] + VOFFB + (P)*KBUFB);    \
                   vf1 = *(const bf16x8*)(kr1[2] + VOFFB + (P)*KBUFB); }       \
      else { vf0 = *(const bf16x8*)(kr0[3] + VOFFB + (P)*KBUFB);               \
             vf1 = *(const bf16x8*)(kr1[3] + VOFFB + (P)*KBUFB); }             \
      oA0 = __builtin_amdgcn_mfma_f32_32x32x16_bf16(puA.v, vf0, oA0, 0,0,0);   \
      oA1 = __builtin_amdgcn_mfma_f32_32x32x16_bf16(puA.v, vf1, oA1, 0,0,0);   \
      oB0 = __builtin_amdgcn_mfma_f32_32x32x16_bf16(puB.v, vf0, oB0, 0,0,0);   \
      oB1 = __builtin_amdgcn_mfma_f32_32x32x16_bf16(puB.v, vf1, oB1, 0,0,0);   \
    }                                                                          \
    __builtin_amdgcn_s_setprio(0);                                             \
    __syncthreads();                                                           \
  }

  for (int t2=0; t2<NT/2; ++t2) {
    ATTN_TILE(0, 2*t2);
    ATTN_TILE(1, 2*t2+1);
  }
#undef ATTN_TILE
#undef MAKE_PU

  // combine hi-halves of the rowsum; write UNNORMALIZED partials
  lpA += __shfl_xor(lpA, 32);
  lpB += __shfl_xor(lpB, 32);
  bf16* pob = po + (size_t)kvh*MTOK*DM;
#pragma unroll
  for (int r=0;r<16;r++) {
    const int qi = (r&3) + 8*(r>>2) + hi*4;
    {
      bf16* op = pob + (size_t)(b*SEQ + q0 + qi)*DM + h*64 + l31;
      op[0]  = (bf16)oA0[r];
      op[32] = (bf16)oA1[r];
    }
    {
      bf16* op = pob + (size_t)(b*SEQ + q0 + 32 + qi)*DM + h*64 + l31;
      op[0]  = (bf16)oB0[r];
      op[32] = (bf16)oB1[r];
    }
  }
  if (hi == 0) {
    lp[((size_t)kvh*MTOK + b*SEQ + q0 + l31)*NHEADS + h]      = lpA;
    lp[((size_t)kvh*MTOK + b*SEQ + q0 + 32 + l31)*NHEADS + h] = lpB;
  }
}

// ---------------- combine: aout = (po0+po1) * qs / (lp0+lp1) ----------------
__global__ __launch_bounds__(256) void combine_kernel(
    const bf16* __restrict__ po, const float* __restrict__ lp,
    const float* __restrict__ q_scale, bf16* __restrict__ aout) {
  const int idx = blockIdx.x*256 + threadIdx.x;     // over MTOK * DM/8
  const int token = idx >> 7;                       // DM/8 = 128
  const int d8 = idx & 127;
  const int d0 = d8 * 8;
  const int h = d8 >> 3;
  bf16x8 a = *(const bf16x8*)(po + (size_t)token*DM + d0);
  bf16x8 b = *(const bf16x8*)(po + (size_t)MTOK*DM + (size_t)token*DM + d0);
  const float l = lp[(size_t)token*NHEADS + h] + lp[((size_t)MTOK + token)*NHEADS + h];
  const float iv = q_scale[h] / l;
  bf16x8 o;
#pragma unroll
  for (int j=0;j<8;j++) o[j] = (bf16)(((float)a[j] + (float)b[j]) * iv);
  *(bf16x8*)(aout + (size_t)token*DM + d0) = o;
}

// ---------------- launch ----------------
extern "C" void kernel_launch(void* const* d_in, const int* in_sizes, int n_in,
                              void* d_out, int out_size, void* d_ws, size_t ws_size,
                              hipStream_t stream) {
  (void)in_sizes; (void)n_in; (void)out_size; (void)ws_size;
  const float* x  = (const float*)d_in[0];
  const float* wq = (const float*)d_in[1];
  const float* bq = (const float*)d_in[2];
  const float* wk = (const float*)d_in[3];
  const float* bk = (const float*)d_in[4];
  const float* wv = (const float*)d_in[5];
  const float* bv = (const float*)d_in[6];
  const float* wo = (const float*)d_in[7];
  const float* bo = (const float*)d_in[8];
  const float* temp = (const float*)d_in[9];
  const float* qsc  = (const float*)d_in[10];

  char* ws = (char*)d_ws;
  bf16* xb    = (bf16*)ws; ws += (size_t)MTOK*DM*2;
  bf16* wqkvb = (bf16*)ws; ws += (size_t)NE*DM*2;
  bf16* wob   = (bf16*)ws; ws += (size_t)DM*DM*2;
  float* bqkv = (float*)ws; ws += (size_t)NE*4;
  bf16* qkv   = (bf16*)ws; ws += (size_t)MTOK*NE*2;
  bf16* vt    = (bf16*)ws; ws += (size_t)NB*NHEADS*DHEAD*SEQ*2;
  bf16* aout  = (bf16*)ws; ws += (size_t)MTOK*DM*2;
  bf16* po    = (bf16*)ws; ws += (size_t)2*MTOK*DM*2;
  float* lp   = (float*)ws; ws += (size_t)2*MTOK*NHEADS*4;

  convert_kernel<<<dim3(1024), dim3(256), 0, stream>>>(x, wq, wk, wv, wo, bq, bk, bv,
                                                       xb, wqkvb, wob, bqkv);
  gemm_deep<0><<<dim3(MTOK/128, NE/128), dim3(256), 0, stream>>>(xb, wqkvb, bqkv, qkv,
                                                                 MTOK, NE, DM);
  transpose_v<<<dim3(SEQ/64, NB*NHEADS), dim3(256), 0, stream>>>(qkv, vt);
  attn_kernel<<<dim3(SEQ/256, NB*NHEADS, 2), dim3(256), 0, stream>>>(qkv, vt, po, lp, temp);
  combine_kernel<<<dim3(MTOK*DM/8/256), dim3(256), 0, stream>>>(po, lp, qsc, aout);
  gemm_deep<1><<<dim3(MTOK/128, DM/128), dim3(256), 0, stream>>>(aout, wob, bo, d_out,
                                                                 MTOK, DM, DM);
}

// Round 19
// 180.120 us; speedup vs baseline: 3.5552x; 1.0665x over previous
//
#include <hip/hip_runtime.h>
#include <hip/hip_bf16.h>
#include <stdint.h>

typedef __bf16 bf16;
typedef __bf16 bf16x8 __attribute__((ext_vector_type(8)));
typedef __bf16 bf16x4 __attribute__((ext_vector_type(4)));
typedef float f32x4 __attribute__((ext_vector_type(4)));
typedef float f32x16 __attribute__((ext_vector_type(16)));

#define NB 4
#define SEQ 2048
#define DM 1024
#define NHEADS 16
#define DHEAD 64
#define MTOK (NB*SEQ)      /* 8192 */
#define NE 3072            /* 3*DM */

__device__ __forceinline__ void gl_lds16(const bf16* g, bf16* l) {
  __builtin_amdgcn_global_load_lds(
      (const __attribute__((address_space(1))) void*)g,
      (__attribute__((address_space(3))) void*)l, 16, 0, 0);
}

__device__ __forceinline__ f32x16 zero16() {
  f32x16 z;
#pragma unroll
  for (int i=0;i<16;i++) z[i]=0.f;
  return z;
}

// ---------------- convert inputs to bf16 ----------------
__global__ __launch_bounds__(256) void convert_kernel(
    const float* __restrict__ x,
    const float* __restrict__ wq, const float* __restrict__ wk,
    const float* __restrict__ wv, const float* __restrict__ wo,
    const float* __restrict__ bq, const float* __restrict__ bk,
    const float* __restrict__ bv,
    bf16* __restrict__ xb, bf16* __restrict__ wqkvb,
    bf16* __restrict__ wob, float* __restrict__ bqkv) {
  int tid = blockIdx.x*blockDim.x + threadIdx.x;
  int nt = gridDim.x*blockDim.x;
  const int NX4 = MTOK*DM/4;
  for (int i = tid; i < NX4; i += nt) {
    float4 v = ((const float4*)x)[i];
    ((bf16x4*)xb)[i] = bf16x4{(bf16)v.x,(bf16)v.y,(bf16)v.z,(bf16)v.w};
  }
  const int NW4 = DM*DM/4;
  for (int i = tid; i < NW4; i += nt) {
    float4 a = ((const float4*)wq)[i];
    ((bf16x4*)wqkvb)[i] = bf16x4{(bf16)a.x,(bf16)a.y,(bf16)a.z,(bf16)a.w};
    float4 b = ((const float4*)wk)[i];
    ((bf16x4*)wqkvb)[i+NW4] = bf16x4{(bf16)b.x,(bf16)b.y,(bf16)b.z,(bf16)b.w};
    float4 c = ((const float4*)wv)[i];
    ((bf16x4*)wqkvb)[i+2*NW4] = bf16x4{(bf16)c.x,(bf16)c.y,(bf16)c.z,(bf16)c.w};
    float4 d = ((const float4*)wo)[i];
    ((bf16x4*)wob)[i] = bf16x4{(bf16)d.x,(bf16)d.y,(bf16)d.z,(bf16)d.w};
  }
  for (int i = tid; i < DM; i += nt) {
    bqkv[i] = bq[i]; bqkv[i+DM] = bk[i]; bqkv[i+2*DM] = bv[i];
  }
}

// ---- GEMM: 128x128, BK=64, dbuf LDS, counted vmcnt(8), XOR-swizzled (R7 exact) ----
template<int OUT_MODE>
__global__ __launch_bounds__(256) void gemm_deep(
    const bf16* __restrict__ A, const bf16* __restrict__ Bm,
    const float* __restrict__ bias, void* __restrict__ Cout,
    int M, int N, int K) {
  __shared__ bf16 As[2][128*64];
  __shared__ bf16 Bs[2][128*64];
  const int bm = blockIdx.x, bn = blockIdx.y;
  const int thr = threadIdx.x;
  const int w = thr>>6, lane = thr&63;
  const int wr = w>>1, wc = w&1;
  const int l4 = lane>>4, lm = lane&15;
  f32x4 acc[4][4];
#pragma unroll
  for (int m=0;m<4;m++)
#pragma unroll
    for (int n=0;n<4;n++) acc[m][n] = f32x4{0.f,0.f,0.f,0.f};

  const bf16* Abase = A + (size_t)bm*128*K;
  const bf16* Bbase = Bm + (size_t)bn*128*K;

  const int srow = thr>>3;
  const int sch  = ((thr&7) ^ (srow&7)) * 8;
  const bf16* Ag = Abase + (size_t)srow*K + sch;
  const bf16* Bg = Bbase + (size_t)srow*K + sch;
  const int dbase = thr*8;

  const int nk = K>>6;

  int aoff[2][4], boff[2][4];
#pragma unroll
  for (int ks=0;ks<2;ks++) {
#pragma unroll
    for (int m=0;m<4;m++) {
      const int r = wr*64 + m*16 + lm;
      aoff[ks][m] = r*64 + ((((ks<<2)|l4) ^ (lm&7))*8);
    }
#pragma unroll
    for (int n=0;n<4;n++) {
      const int r = wc*64 + n*16 + lm;
      boff[ks][n] = r*64 + ((((ks<<2)|l4) ^ (lm&7))*8);
    }
  }

#pragma unroll
  for (int c=0;c<4;c++) {
    gl_lds16(Ag + (size_t)c*32*K, &As[0][c*2048 + dbase]);
    gl_lds16(Bg + (size_t)c*32*K, &Bs[0][c*2048 + dbase]);
  }

  for (int kt=0; kt<nk; ++kt) {
    const int p = kt&1;
    const int st = (kt+1 < nk) ? kt+1 : 0;
    const size_t ko = (size_t)st*64;
#pragma unroll
    for (int c=0;c<4;c++) {
      gl_lds16(Ag + ko + (size_t)c*32*K, &As[p^1][c*2048 + dbase]);
      gl_lds16(Bg + ko + (size_t)c*32*K, &Bs[p^1][c*2048 + dbase]);
    }
    asm volatile("s_waitcnt vmcnt(8)" ::: "memory");
    __builtin_amdgcn_s_barrier();
    __builtin_amdgcn_sched_barrier(0);

    const bf16* Ac = As[p];
    const bf16* Bc = Bs[p];
    __builtin_amdgcn_s_setprio(1);
#pragma unroll
    for (int ks=0;ks<2;ks++) {
      bf16x8 af[4], bfr[4];
#pragma unroll
      for (int m=0;m<4;m++) af[m] = *(const bf16x8*)&Ac[aoff[ks][m]];
#pragma unroll
      for (int n=0;n<4;n++) bfr[n] = *(const bf16x8*)&Bc[boff[ks][n]];
#pragma unroll
      for (int m=0;m<4;m++)
#pragma unroll
        for (int n=0;n<4;n++)
          acc[m][n] = __builtin_amdgcn_mfma_f32_16x16x32_bf16(af[m], bfr[n], acc[m][n], 0, 0, 0);
    }
    __builtin_amdgcn_s_setprio(0);
    __builtin_amdgcn_s_barrier();
    __builtin_amdgcn_sched_barrier(0);
  }

  const int rbase = bm*128 + wr*64 + l4*4;
  const int cbase = bn*128 + wc*64;
#pragma unroll
  for (int n=0;n<4;n++) {
    const int col = cbase + n*16 + lm;
    const float bv = bias[col];
#pragma unroll
    for (int m=0;m<4;m++) {
#pragma unroll
      for (int j=0;j<4;j++) {
        const int row = rbase + m*16 + j;
        const float v = acc[m][n][j] + bv;
        if (OUT_MODE == 0) ((bf16*)Cout)[(size_t)row*N + col] = (bf16)v;
        else               ((float*)Cout)[(size_t)row*N + col] = v;
      }
    }
  }
}

// ---------------- transpose V: qkv[b,s, 2048+h*64+d] -> vt[b,h,d,s] ----------------
__global__ __launch_bounds__(256) void transpose_v(const bf16* __restrict__ qkv,
                                                   bf16* __restrict__ vt) {
  __shared__ bf16 tile[64*72];
  const int s0 = blockIdx.x*64;
  const int bh = blockIdx.y;
  const bf16* src = qkv + (size_t)((bh>>4)*SEQ + s0)*NE + 2*DM + (bh&15)*64;
  const int thr = threadIdx.x;
#pragma unroll
  for (int i=0;i<2;i++) {
    int idx = thr + i*256;
    int row = idx>>3, part = idx&7;
    *(bf16x8*)&tile[row*72 + part*8] = *(const bf16x8*)(src + (size_t)row*NE + part*8);
  }
  __syncthreads();
  bf16* dst = vt + (size_t)bh*64*SEQ + s0;
#pragma unroll
  for (int i=0;i<2;i++) {
    int idx = thr + i*256;
    int d = idx>>3, part = idx&7;
    bf16x8 v;
#pragma unroll
    for (int j=0;j<8;j++) v[j] = tile[(part*8+j)*72 + d];
    *(bf16x8*)(dst + (size_t)d*SEQ + part*8) = v;
  }
}

// ---------------- flash attention: 4 waves x 64 q-rows (2 q-halves/wave) ----
// grid: (SEQ/256, NB*NHEADS), block 256, 2 blocks/CU. R15 exact bits (75.4 us):
// lane-local f32 rowsum in the exp loops, shfl redistribution in epilogue.
__global__ __launch_bounds__(256, 2) void attn_kernel(
    const bf16* __restrict__ qkv, const bf16* __restrict__ vt,
    bf16* __restrict__ aout,
    const float* __restrict__ temperature, const float* __restrict__ q_scale) {
  __shared__ bf16 smem[4][64*64];   // [K0][K1][V0][V1], rows 128B, XOR-swizzled 16B chunks
  const int bh = blockIdx.y;
  const int b = bh>>4, h = bh&15;
  const int thr = threadIdx.x;
  const int w = thr>>6, lane = thr&63;
  const int l31 = lane&31, hi = lane>>5;
  const float sc2 = 1.4426950408889634f / (8.0f * temperature[0]);
  const int q0 = blockIdx.x*256 + w*64;
  const int NT = SEQ/64;
#define KBUFB 8192        /* bytes per buffer */
#define VOFFB 16384       /* V region byte offset */

  // Q fragments for both q-halves, pre-scaled by sc2
  bf16x8 qfA[4], qfB[4];
  {
    const bf16* qpA = qkv + (size_t)(b*SEQ + q0 + l31)*NE + h*64 + hi*8;
    const bf16* qpB = qpA + (size_t)32*NE;
#pragma unroll
    for (int s=0;s<4;s++) {
      bf16x8 qa = *(const bf16x8*)(qpA + s*16);
      bf16x8 qb = *(const bf16x8*)(qpB + s*16);
#pragma unroll
      for (int j=0;j<8;j++) {
        qfA[s][j] = (bf16)((float)qa[j] * sc2);
        qfB[s][j] = (bf16)((float)qb[j] * sc2);
      }
    }
  }

  f32x16 oA0 = zero16(), oA1 = zero16();
  f32x16 oB0 = zero16(), oB1 = zero16();
  float lpA = 0.f, lpB = 0.f;     // lane-local rowsum for q = lane&31 (this hi-half's k)

  const bf16* Kbase = qkv + (size_t)b*SEQ*NE + DM + h*64;
  const bf16* Vbase = vt + (size_t)bh*64*SEQ;

  // staging: thread -> row sr (0..63), chunk scb (0..3); swizzle chunk^=(row&7)
  const int sr = thr>>2, scb = thr&3;
  const int wb0 = sr*128 + (((scb*2+0) ^ (sr&7))<<4);
  const int wb1 = sr*128 + (((scb*2+1) ^ (sr&7))<<4);
  const int rsw = l31&7;

  // precomputed fragment read addresses; buffer/V region via imm offsets
  const char* kr0[4];
  const char* kr1[4];
#pragma unroll
  for (int s=0;s<4;s++) {
    const int slot = s*2 + hi;
    kr0[s] = (const char*)smem + l31*128      + ((slot ^ rsw)<<4);
    kr1[s] = (const char*)smem + (32+l31)*128 + ((slot ^ rsw)<<4);
  }

  const bf16* kgb = Kbase + (size_t)sr*NE + scb*16;
  const bf16* vgb = Vbase + (size_t)sr*SEQ + scb*16;

  bf16x8 ka, kb, va, vb;
  ka = *(const bf16x8*)(kgb);
  kb = *(const bf16x8*)(kgb + 8);
  va = *(const bf16x8*)(vgb);
  vb = *(const bf16x8*)(vgb + 8);
  *(bf16x8*)((char*)smem + wb0)         = ka;
  *(bf16x8*)((char*)smem + wb1)         = kb;
  *(bf16x8*)((char*)smem + VOFFB + wb0) = va;
  *(bf16x8*)((char*)smem + VOFFB + wb1) = vb;
  kgb += (size_t)64*NE; vgb += 64;
  ka = *(const bf16x8*)(kgb);
  kb = *(const bf16x8*)(kgb + 8);
  va = *(const bf16x8*)(vgb);
  vb = *(const bf16x8*)(vgb + 8);
  kgb += (size_t)64*NE; vgb += 64;
  __syncthreads();

#define MAKE_PU(PU, S0, S1, KS)                                                \
  { float e0,e1,e2,e3,e4,e5,e6,e7;                                             \
    if ((KS)==0)      { e0=S0[0]; e1=S0[1]; e2=S0[2]; e3=S0[3];                \
                        e4=S0[4]; e5=S0[5]; e6=S0[6]; e7=S0[7]; }              \
    else if ((KS)==1) { e0=S0[8]; e1=S0[9]; e2=S0[10];e3=S0[11];               \
                        e4=S0[12];e5=S0[13];e6=S0[14];e7=S0[15]; }             \
    else if ((KS)==2) { e0=S1[0]; e1=S1[1]; e2=S1[2]; e3=S1[3];                \
                        e4=S1[4]; e5=S1[5]; e6=S1[6]; e7=S1[7]; }              \
    else              { e0=S1[8]; e1=S1[9]; e2=S1[10];e3=S1[11];               \
                        e4=S1[12];e5=S1[13];e6=S1[14];e7=S1[15]; }             \
    unsigned a0,a1,b0,b1;                                                      \
    asm("v_cvt_pk_bf16_f32 %0, %1, %2" : "=v"(a0) : "v"(e0), "v"(e1));         \
    asm("v_cvt_pk_bf16_f32 %0, %1, %2" : "=v"(a1) : "v"(e2), "v"(e3));         \
    asm("v_cvt_pk_bf16_f32 %0, %1, %2" : "=v"(b0) : "v"(e4), "v"(e5));         \
    asm("v_cvt_pk_bf16_f32 %0, %1, %2" : "=v"(b1) : "v"(e6), "v"(e7));         \
    asm("v_permlane32_swap_b32 %0, %1" : "+v"(a0), "+v"(b0));                  \
    asm("v_permlane32_swap_b32 %0, %1" : "+v"(a1), "+v"(b1));                  \
    PU.u[0]=a0; PU.u[1]=a1; PU.u[2]=b0; PU.u[3]=b1; }

#define ATTN_TILE(P, T)                                                        \
  {                                                                            \
    const int t_ = (T);                                                        \
    if (t_ < NT-1) {                                                           \
      *(bf16x8*)((char*)smem + ((P)^1)*KBUFB + wb0)         = ka;              \
      *(bf16x8*)((char*)smem + ((P)^1)*KBUFB + wb1)         = kb;              \
      *(bf16x8*)((char*)smem + VOFFB + ((P)^1)*KBUFB + wb0) = va;              \
      *(bf16x8*)((char*)smem + VOFFB + ((P)^1)*KBUFB + wb1) = vb;              \
      if (t_ < NT-2) {                                                         \
        ka = *(const bf16x8*)(kgb);                                            \
        kb = *(const bf16x8*)(kgb + 8);                                        \
        va = *(const bf16x8*)(vgb);                                            \
        vb = *(const bf16x8*)(vgb + 8);                                        \
        kgb += (size_t)64*NE; vgb += 64;                                       \
      }                                                                        \
    }                                                                          \
    f32x16 sA0 = zero16(), sA1 = zero16(), sB0 = zero16(), sB1 = zero16();     \
    __builtin_amdgcn_s_setprio(1);                                             \
    _Pragma("unroll")                                                          \
    for (int s=0;s<4;s++) {                                                    \
      bf16x8 kf0 = *(const bf16x8*)(kr0[s] + (P)*KBUFB);                       \
      bf16x8 kf1 = *(const bf16x8*)(kr1[s] + (P)*KBUFB);                       \
      sA0 = __builtin_amdgcn_mfma_f32_32x32x16_bf16(kf0, qfA[s], sA0, 0,0,0);  \
      sB0 = __builtin_amdgcn_mfma_f32_32x32x16_bf16(kf0, qfB[s], sB0, 0,0,0);  \
      sA1 = __builtin_amdgcn_mfma_f32_32x32x16_bf16(kf1, qfA[s], sA1, 0,0,0);  \
      sB1 = __builtin_amdgcn_mfma_f32_32x32x16_bf16(kf1, qfB[s], sB1, 0,0,0);  \
    }                                                                          \
    __builtin_amdgcn_s_setprio(0);                                             \
    _Pragma("unroll")                                                          \
    for (int r=0;r<16;r++) { sA0[r] = __builtin_amdgcn_exp2f(sA0[r]); lpA += sA0[r]; } \
    _Pragma("unroll")                                                          \
    for (int r=0;r<16;r++) { sA1[r] = __builtin_amdgcn_exp2f(sA1[r]); lpA += sA1[r]; } \
    _Pragma("unroll")                                                          \
    for (int r=0;r<16;r++) { sB0[r] = __builtin_amdgcn_exp2f(sB0[r]); lpB += sB0[r]; } \
    _Pragma("unroll")                                                          \
    for (int r=0;r<16;r++) { sB1[r] = __builtin_amdgcn_exp2f(sB1[r]); lpB += sB1[r]; } \
    __builtin_amdgcn_s_setprio(1);                                             \
    _Pragma("unroll")                                                          \
    for (int ks=0;ks<4;ks++) {                                                 \
      union { unsigned u[4]; bf16x8 v; } puA, puB;                             \
      MAKE_PU(puA, sA0, sA1, ks);                                              \
      MAKE_PU(puB, sB0, sB1, ks);                                              \
      bf16x8 vf0, vf1;                                                         \
      if (ks==0) { vf0 = *(const bf16x8*)(kr0[0] + VOFFB + (P)*KBUFB);         \
                   vf1 = *(const bf16x8*)(kr1[0] + VOFFB + (P)*KBUFB); }       \
      else if (ks==1) { vf0 = *(const bf16x8*)(kr0[1] + VOFFB + (P)*KBUFB);    \
                   vf1 = *(const bf16x8*)(kr1[1] + VOFFB + (P)*KBUFB); }       \
      else if (ks==2) { vf0 = *(const bf16x8*)(kr0[2] + VOFFB + (P)*KBUFB);    \
                   vf1 = *(const bf16x8*)(kr1[2] + VOFFB + (P)*KBUFB); }       \
      else { vf0 = *(const bf16x8*)(kr0[3] + VOFFB + (P)*KBUFB);               \
             vf1 = *(const bf16x8*)(kr1[3] + VOFFB + (P)*KBUFB); }             \
      oA0 = __builtin_amdgcn_mfma_f32_32x32x16_bf16(puA.v, vf0, oA0, 0,0,0);   \
      oA1 = __builtin_amdgcn_mfma_f32_32x32x16_bf16(puA.v, vf1, oA1, 0,0,0);   \
      oB0 = __builtin_amdgcn_mfma_f32_32x32x16_bf16(puB.v, vf0, oB0, 0,0,0);   \
      oB1 = __builtin_amdgcn_mfma_f32_32x32x16_bf16(puB.v, vf1, oB1, 0,0,0);   \
    }                                                                          \
    __builtin_amdgcn_s_setprio(0);                                             \
    __syncthreads();                                                           \
  }

  for (int t2=0; t2<NT/2; ++t2) {
    ATTN_TILE(0, 2*t2);
    ATTN_TILE(1, 2*t2+1);
  }
#undef ATTN_TILE
#undef MAKE_PU

  // combine hi-halves of the rowsum, then one reciprocal per q-half per lane
  lpA += __shfl_xor(lpA, 32);
  lpB += __shfl_xor(lpB, 32);
  const float qs = q_scale[h];
  const float ivA_lane = qs / lpA;   // valid for q = lane&31
  const float ivB_lane = qs / lpB;
#pragma unroll
  for (int r=0;r<16;r++) {
    const int qi = (r&3) + 8*(r>>2) + hi*4;
    {
      const float iv = __shfl(ivA_lane, qi);
      bf16* op = aout + (size_t)(b*SEQ + q0 + qi)*DM + h*64 + l31;
      op[0]  = (bf16)(oA0[r]*iv);
      op[32] = (bf16)(oA1[r]*iv);
    }
    {
      const float iv = __shfl(ivB_lane, qi);
      bf16* op = aout + (size_t)(b*SEQ + q0 + 32 + qi)*DM + h*64 + l31;
      op[0]  = (bf16)(oB0[r]*iv);
      op[32] = (bf16)(oB1[r]*iv);
    }
  }
}

// ---------------- launch ----------------
extern "C" void kernel_launch(void* const* d_in, const int* in_sizes, int n_in,
                              void* d_out, int out_size, void* d_ws, size_t ws_size,
                              hipStream_t stream) {
  (void)in_sizes; (void)n_in; (void)out_size; (void)ws_size;
  const float* x  = (const float*)d_in[0];
  const float* wq = (const float*)d_in[1];
  const float* bq = (const float*)d_in[2];
  const float* wk = (const float*)d_in[3];
  const float* bk = (const float*)d_in[4];
  const float* wv = (const float*)d_in[5];
  const float* bv = (const float*)d_in[6];
  const float* wo = (const float*)d_in[7];
  const float* bo = (const float*)d_in[8];
  const float* temp = (const float*)d_in[9];
  const float* qsc  = (const float*)d_in[10];

  char* ws = (char*)d_ws;
  bf16* xb    = (bf16*)ws; ws += (size_t)MTOK*DM*2;
  bf16* wqkvb = (bf16*)ws; ws += (size_t)NE*DM*2;
  bf16* wob   = (bf16*)ws; ws += (size_t)DM*DM*2;
  float* bqkv = (float*)ws; ws += (size_t)NE*4;
  bf16* qkv   = (bf16*)ws; ws += (size_t)MTOK*NE*2;
  bf16* vt    = (bf16*)ws; ws += (size_t)NB*NHEADS*DHEAD*SEQ*2;
  bf16* aout  = (bf16*)ws; ws += (size_t)MTOK*DM*2;

  convert_kernel<<<dim3(1024), dim3(256), 0, stream>>>(x, wq, wk, wv, wo, bq, bk, bv,
                                                       xb, wqkvb, wob, bqkv);
  gemm_deep<0><<<dim3(MTOK/128, NE/128), dim3(256), 0, stream>>>(xb, wqkvb, bqkv, qkv,
                                                                 MTOK, NE, DM);
  transpose_v<<<dim3(SEQ/64, NB*NHEADS), dim3(256), 0, stream>>>(qkv, vt);
  attn_kernel<<<dim3(SEQ/256, NB*NHEADS), dim3(256), 0, stream>>>(qkv, vt, aout, temp, qsc);
  gemm_deep<1><<<dim3(MTOK/128, DM/128), dim3(256), 0, stream>>>(aout, wob, bo, d_out,
                                                                 MTOK, DM, DM);
}

// Round 20
// 175.999 us; speedup vs baseline: 3.6384x; 1.0234x over previous
//
#include <hip/hip_runtime.h>
#include <hip/hip_bf16.h>
#include <stdint.h>

typedef __bf16 bf16;
typedef __bf16 bf16x8 __attribute__((ext_vector_type(8)));
typedef __bf16 bf16x4 __attribute__((ext_vector_type(4)));
typedef float f32x4 __attribute__((ext_vector_type(4)));
typedef float f32x16 __attribute__((ext_vector_type(16)));

#define NB 4
#define SEQ 2048
#define DM 1024
#define NHEADS 16
#define DHEAD 64
#define MTOK (NB*SEQ)      /* 8192 */
#define NE 3072            /* 3*DM */

__device__ __forceinline__ void gl_lds16(const bf16* g, bf16* l) {
  __builtin_amdgcn_global_load_lds(
      (const __attribute__((address_space(1))) void*)g,
      (__attribute__((address_space(3))) void*)l, 16, 0, 0);
}

__device__ __forceinline__ f32x16 zero16() {
  f32x16 z;
#pragma unroll
  for (int i=0;i<16;i++) z[i]=0.f;
  return z;
}

// ---------------- convert inputs to bf16 ----------------
__global__ __launch_bounds__(256) void convert_kernel(
    const float* __restrict__ x,
    const float* __restrict__ wq, const float* __restrict__ wk,
    const float* __restrict__ wv, const float* __restrict__ wo,
    const float* __restrict__ bq, const float* __restrict__ bk,
    const float* __restrict__ bv,
    bf16* __restrict__ xb, bf16* __restrict__ wqkvb,
    bf16* __restrict__ wob, float* __restrict__ bqkv) {
  int tid = blockIdx.x*blockDim.x + threadIdx.x;
  int nt = gridDim.x*blockDim.x;
  const int NX4 = MTOK*DM/4;
  for (int i = tid; i < NX4; i += nt) {
    float4 v = ((const float4*)x)[i];
    ((bf16x4*)xb)[i] = bf16x4{(bf16)v.x,(bf16)v.y,(bf16)v.z,(bf16)v.w};
  }
  const int NW4 = DM*DM/4;
  for (int i = tid; i < NW4; i += nt) {
    float4 a = ((const float4*)wq)[i];
    ((bf16x4*)wqkvb)[i] = bf16x4{(bf16)a.x,(bf16)a.y,(bf16)a.z,(bf16)a.w};
    float4 b = ((const float4*)wk)[i];
    ((bf16x4*)wqkvb)[i+NW4] = bf16x4{(bf16)b.x,(bf16)b.y,(bf16)b.z,(bf16)b.w};
    float4 c = ((const float4*)wv)[i];
    ((bf16x4*)wqkvb)[i+2*NW4] = bf16x4{(bf16)c.x,(bf16)c.y,(bf16)c.z,(bf16)c.w};
    float4 d = ((const float4*)wo)[i];
    ((bf16x4*)wob)[i] = bf16x4{(bf16)d.x,(bf16)d.y,(bf16)d.z,(bf16)d.w};
  }
  for (int i = tid; i < DM; i += nt) {
    bqkv[i] = bq[i]; bqkv[i+DM] = bk[i]; bqkv[i+2*DM] = bv[i];
  }
}

// ---- GEMM: 128x128, BK=64, dbuf LDS, counted vmcnt(8), XOR-swizzled (R7 exact) ----
template<int OUT_MODE>
__global__ __launch_bounds__(256) void gemm_deep(
    const bf16* __restrict__ A, const bf16* __restrict__ Bm,
    const float* __restrict__ bias, void* __restrict__ Cout,
    int M, int N, int K) {
  __shared__ bf16 As[2][128*64];
  __shared__ bf16 Bs[2][128*64];
  const int bm = blockIdx.x, bn = blockIdx.y;
  const int thr = threadIdx.x;
  const int w = thr>>6, lane = thr&63;
  const int wr = w>>1, wc = w&1;
  const int l4 = lane>>4, lm = lane&15;
  f32x4 acc[4][4];
#pragma unroll
  for (int m=0;m<4;m++)
#pragma unroll
    for (int n=0;n<4;n++) acc[m][n] = f32x4{0.f,0.f,0.f,0.f};

  const bf16* Abase = A + (size_t)bm*128*K;
  const bf16* Bbase = Bm + (size_t)bn*128*K;

  const int srow = thr>>3;
  const int sch  = ((thr&7) ^ (srow&7)) * 8;
  const bf16* Ag = Abase + (size_t)srow*K + sch;
  const bf16* Bg = Bbase + (size_t)srow*K + sch;
  const int dbase = thr*8;

  const int nk = K>>6;

  int aoff[2][4], boff[2][4];
#pragma unroll
  for (int ks=0;ks<2;ks++) {
#pragma unroll
    for (int m=0;m<4;m++) {
      const int r = wr*64 + m*16 + lm;
      aoff[ks][m] = r*64 + ((((ks<<2)|l4) ^ (lm&7))*8);
    }
#pragma unroll
    for (int n=0;n<4;n++) {
      const int r = wc*64 + n*16 + lm;
      boff[ks][n] = r*64 + ((((ks<<2)|l4) ^ (lm&7))*8);
    }
  }

#pragma unroll
  for (int c=0;c<4;c++) {
    gl_lds16(Ag + (size_t)c*32*K, &As[0][c*2048 + dbase]);
    gl_lds16(Bg + (size_t)c*32*K, &Bs[0][c*2048 + dbase]);
  }

  for (int kt=0; kt<nk; ++kt) {
    const int p = kt&1;
    const int st = (kt+1 < nk) ? kt+1 : 0;
    const size_t ko = (size_t)st*64;
#pragma unroll
    for (int c=0;c<4;c++) {
      gl_lds16(Ag + ko + (size_t)c*32*K, &As[p^1][c*2048 + dbase]);
      gl_lds16(Bg + ko + (size_t)c*32*K, &Bs[p^1][c*2048 + dbase]);
    }
    asm volatile("s_waitcnt vmcnt(8)" ::: "memory");
    __builtin_amdgcn_s_barrier();
    __builtin_amdgcn_sched_barrier(0);

    const bf16* Ac = As[p];
    const bf16* Bc = Bs[p];
    __builtin_amdgcn_s_setprio(1);
#pragma unroll
    for (int ks=0;ks<2;ks++) {
      bf16x8 af[4], bfr[4];
#pragma unroll
      for (int m=0;m<4;m++) af[m] = *(const bf16x8*)&Ac[aoff[ks][m]];
#pragma unroll
      for (int n=0;n<4;n++) bfr[n] = *(const bf16x8*)&Bc[boff[ks][n]];
#pragma unroll
      for (int m=0;m<4;m++)
#pragma unroll
        for (int n=0;n<4;n++)
          acc[m][n] = __builtin_amdgcn_mfma_f32_16x16x32_bf16(af[m], bfr[n], acc[m][n], 0, 0, 0);
    }
    __builtin_amdgcn_s_setprio(0);
    __builtin_amdgcn_s_barrier();
    __builtin_amdgcn_sched_barrier(0);
  }

  const int rbase = bm*128 + wr*64 + l4*4;
  const int cbase = bn*128 + wc*64;
#pragma unroll
  for (int n=0;n<4;n++) {
    const int col = cbase + n*16 + lm;
    const float bv = bias[col];
#pragma unroll
    for (int m=0;m<4;m++) {
#pragma unroll
      for (int j=0;j<4;j++) {
        const int row = rbase + m*16 + j;
        const float v = acc[m][n][j] + bv;
        if (OUT_MODE == 0) ((bf16*)Cout)[(size_t)row*N + col] = (bf16)v;
        else               ((float*)Cout)[(size_t)row*N + col] = v;
      }
    }
  }
}

// ---------------- transpose V: qkv[b,s, 2048+h*64+d] -> vt[b,h,d,s] ----------------
__global__ __launch_bounds__(256) void transpose_v(const bf16* __restrict__ qkv,
                                                   bf16* __restrict__ vt) {
  __shared__ bf16 tile[64*72];
  const int s0 = blockIdx.x*64;
  const int bh = blockIdx.y;
  const bf16* src = qkv + (size_t)((bh>>4)*SEQ + s0)*NE + 2*DM + (bh&15)*64;
  const int thr = threadIdx.x;
#pragma unroll
  for (int i=0;i<2;i++) {
    int idx = thr + i*256;
    int row = idx>>3, part = idx&7;
    *(bf16x8*)&tile[row*72 + part*8] = *(const bf16x8*)(src + (size_t)row*NE + part*8);
  }
  __syncthreads();
  bf16* dst = vt + (size_t)bh*64*SEQ + s0;
#pragma unroll
  for (int i=0;i<2;i++) {
    int idx = thr + i*256;
    int d = idx>>3, part = idx&7;
    bf16x8 v;
#pragma unroll
    for (int j=0;j<8;j++) v[j] = tile[(part*8+j)*72 + d];
    *(bf16x8*)(dst + (size_t)d*SEQ + part*8) = v;
  }
}

// ---------------- flash attention: 4 waves x 64 q-rows (2 q-halves/wave) ----
// grid: 512 blocks (1-D, XCD-chunked: xcd = flat&7 owns a complete bh-octet so
// the 8 q-blocks sharing one (b,h)'s K/V co-locate on one XCD -> K/V L2-local).
// Main loop = R15 exact bits (75.4 us).
__global__ __launch_bounds__(256, 2) void attn_kernel(
    const bf16* __restrict__ qkv, const bf16* __restrict__ vt,
    bf16* __restrict__ aout,
    const float* __restrict__ temperature, const float* __restrict__ q_scale) {
  __shared__ bf16 smem[4][64*64];   // [K0][K1][V0][V1], rows 128B, XOR-swizzled 16B chunks
  const int flat = blockIdx.x;              // 0..511
  const int xcd = flat & 7, local = flat >> 3;
  const int bh = xcd*8 + (local>>3);        // 8 bh per XCD
  const int qb = local & 7;                 // q-block within bh
  const int b = bh>>4, h = bh&15;
  const int thr = threadIdx.x;
  const int w = thr>>6, lane = thr&63;
  const int l31 = lane&31, hi = lane>>5;
  const float sc2 = 1.4426950408889634f / (8.0f * temperature[0]);
  const int q0 = qb*256 + w*64;
  const int NT = SEQ/64;
#define KBUFB 8192        /* bytes per buffer */
#define VOFFB 16384       /* V region byte offset */

  // Q fragments for both q-halves, pre-scaled by sc2
  bf16x8 qfA[4], qfB[4];
  {
    const bf16* qpA = qkv + (size_t)(b*SEQ + q0 + l31)*NE + h*64 + hi*8;
    const bf16* qpB = qpA + (size_t)32*NE;
#pragma unroll
    for (int s=0;s<4;s++) {
      bf16x8 qa = *(const bf16x8*)(qpA + s*16);
      bf16x8 qb_ = *(const bf16x8*)(qpB + s*16);
#pragma unroll
      for (int j=0;j<8;j++) {
        qfA[s][j] = (bf16)((float)qa[j] * sc2);
        qfB[s][j] = (bf16)((float)qb_[j] * sc2);
      }
    }
  }

  f32x16 oA0 = zero16(), oA1 = zero16();
  f32x16 oB0 = zero16(), oB1 = zero16();
  float lpA = 0.f, lpB = 0.f;     // lane-local rowsum for q = lane&31 (this hi-half's k)

  const bf16* Kbase = qkv + (size_t)b*SEQ*NE + DM + h*64;
  const bf16* Vbase = vt + (size_t)bh*64*SEQ;

  // staging: thread -> row sr (0..63), chunk scb (0..3); swizzle chunk^=(row&7)
  const int sr = thr>>2, scb = thr&3;
  const int wb0 = sr*128 + (((scb*2+0) ^ (sr&7))<<4);
  const int wb1 = sr*128 + (((scb*2+1) ^ (sr&7))<<4);
  const int rsw = l31&7;

  // precomputed fragment read addresses; buffer/V region via imm offsets
  const char* kr0[4];
  const char* kr1[4];
#pragma unroll
  for (int s=0;s<4;s++) {
    const int slot = s*2 + hi;
    kr0[s] = (const char*)smem + l31*128      + ((slot ^ rsw)<<4);
    kr1[s] = (const char*)smem + (32+l31)*128 + ((slot ^ rsw)<<4);
  }

  const bf16* kgb = Kbase + (size_t)sr*NE + scb*16;
  const bf16* vgb = Vbase + (size_t)sr*SEQ + scb*16;

  bf16x8 ka, kb, va, vb;
  ka = *(const bf16x8*)(kgb);
  kb = *(const bf16x8*)(kgb + 8);
  va = *(const bf16x8*)(vgb);
  vb = *(const bf16x8*)(vgb + 8);
  *(bf16x8*)((char*)smem + wb0)         = ka;
  *(bf16x8*)((char*)smem + wb1)         = kb;
  *(bf16x8*)((char*)smem + VOFFB + wb0) = va;
  *(bf16x8*)((char*)smem + VOFFB + wb1) = vb;
  kgb += (size_t)64*NE; vgb += 64;
  ka = *(const bf16x8*)(kgb);
  kb = *(const bf16x8*)(kgb + 8);
  va = *(const bf16x8*)(vgb);
  vb = *(const bf16x8*)(vgb + 8);
  kgb += (size_t)64*NE; vgb += 64;
  __syncthreads();

#define MAKE_PU(PU, S0, S1, KS)                                                \
  { float e0,e1,e2,e3,e4,e5,e6,e7;                                             \
    if ((KS)==0)      { e0=S0[0]; e1=S0[1]; e2=S0[2]; e3=S0[3];                \
                        e4=S0[4]; e5=S0[5]; e6=S0[6]; e7=S0[7]; }              \
    else if ((KS)==1) { e0=S0[8]; e1=S0[9]; e2=S0[10];e3=S0[11];               \
                        e4=S0[12];e5=S0[13];e6=S0[14];e7=S0[15]; }             \
    else if ((KS)==2) { e0=S1[0]; e1=S1[1]; e2=S1[2]; e3=S1[3];                \
                        e4=S1[4]; e5=S1[5]; e6=S1[6]; e7=S1[7]; }              \
    else              { e0=S1[8]; e1=S1[9]; e2=S1[10];e3=S1[11];               \
                        e4=S1[12];e5=S1[13];e6=S1[14];e7=S1[15]; }             \
    unsigned a0,a1,b0,b1;                                                      \
    asm("v_cvt_pk_bf16_f32 %0, %1, %2" : "=v"(a0) : "v"(e0), "v"(e1));         \
    asm("v_cvt_pk_bf16_f32 %0, %1, %2" : "=v"(a1) : "v"(e2), "v"(e3));         \
    asm("v_cvt_pk_bf16_f32 %0, %1, %2" : "=v"(b0) : "v"(e4), "v"(e5));         \
    asm("v_cvt_pk_bf16_f32 %0, %1, %2" : "=v"(b1) : "v"(e6), "v"(e7));         \
    asm("v_permlane32_swap_b32 %0, %1" : "+v"(a0), "+v"(b0));                  \
    asm("v_permlane32_swap_b32 %0, %1" : "+v"(a1), "+v"(b1));                  \
    PU.u[0]=a0; PU.u[1]=a1; PU.u[2]=b0; PU.u[3]=b1; }

#define ATTN_TILE(P, T)                                                        \
  {                                                                            \
    const int t_ = (T);                                                        \
    if (t_ < NT-1) {                                                           \
      *(bf16x8*)((char*)smem + ((P)^1)*KBUFB + wb0)         = ka;              \
      *(bf16x8*)((char*)smem + ((P)^1)*KBUFB + wb1)         = kb;              \
      *(bf16x8*)((char*)smem + VOFFB + ((P)^1)*KBUFB + wb0) = va;              \
      *(bf16x8*)((char*)smem + VOFFB + ((P)^1)*KBUFB + wb1) = vb;              \
      if (t_ < NT-2) {                                                         \
        ka = *(const bf16x8*)(kgb);                                            \
        kb = *(const bf16x8*)(kgb + 8);                                        \
        va = *(const bf16x8*)(vgb);                                            \
        vb = *(const bf16x8*)(vgb + 8);                                        \
        kgb += (size_t)64*NE; vgb += 64;                                       \
      }                                                                        \
    }                                                                          \
    f32x16 sA0 = zero16(), sA1 = zero16(), sB0 = zero16(), sB1 = zero16();     \
    __builtin_amdgcn_s_setprio(1);                                             \
    _Pragma("unroll")                                                          \
    for (int s=0;s<4;s++) {                                                    \
      bf16x8 kf0 = *(const bf16x8*)(kr0[s] + (P)*KBUFB);                       \
      bf16x8 kf1 = *(const bf16x8*)(kr1[s] + (P)*KBUFB);                       \
      sA0 = __builtin_amdgcn_mfma_f32_32x32x16_bf16(kf0, qfA[s], sA0, 0,0,0);  \
      sB0 = __builtin_amdgcn_mfma_f32_32x32x16_bf16(kf0, qfB[s], sB0, 0,0,0);  \
      sA1 = __builtin_amdgcn_mfma_f32_32x32x16_bf16(kf1, qfA[s], sA1, 0,0,0);  \
      sB1 = __builtin_amdgcn_mfma_f32_32x32x16_bf16(kf1, qfB[s], sB1, 0,0,0);  \
    }                                                                          \
    __builtin_amdgcn_s_setprio(0);                                             \
    _Pragma("unroll")                                                          \
    for (int r=0;r<16;r++) { sA0[r] = __builtin_amdgcn_exp2f(sA0[r]); lpA += sA0[r]; } \
    _Pragma("unroll")                                                          \
    for (int r=0;r<16;r++) { sA1[r] = __builtin_amdgcn_exp2f(sA1[r]); lpA += sA1[r]; } \
    _Pragma("unroll")                                                          \
    for (int r=0;r<16;r++) { sB0[r] = __builtin_amdgcn_exp2f(sB0[r]); lpB += sB0[r]; } \
    _Pragma("unroll")                                                          \
    for (int r=0;r<16;r++) { sB1[r] = __builtin_amdgcn_exp2f(sB1[r]); lpB += sB1[r]; } \
    __builtin_amdgcn_s_setprio(1);                                             \
    _Pragma("unroll")                                                          \
    for (int ks=0;ks<4;ks++) {                                                 \
      union { unsigned u[4]; bf16x8 v; } puA, puB;                             \
      MAKE_PU(puA, sA0, sA1, ks);                                              \
      MAKE_PU(puB, sB0, sB1, ks);                                              \
      bf16x8 vf0, vf1;                                                         \
      if (ks==0) { vf0 = *(const bf16x8*)(kr0[0] + VOFFB + (P)*KBUFB);         \
                   vf1 = *(const bf16x8*)(kr1[0] + VOFFB + (P)*KBUFB); }       \
      else if (ks==1) { vf0 = *(const bf16x8*)(kr0[1] + VOFFB + (P)*KBUFB);    \
                   vf1 = *(const bf16x8*)(kr1[1] + VOFFB + (P)*KBUFB); }       \
      else if (ks==2) { vf0 = *(const bf16x8*)(kr0[2] + VOFFB + (P)*KBUFB);    \
                   vf1 = *(const bf16x8*)(kr1[2] + VOFFB + (P)*KBUFB); }       \
      else { vf0 = *(const bf16x8*)(kr0[3] + VOFFB + (P)*KBUFB);               \
             vf1 = *(const bf16x8*)(kr1[3] + VOFFB + (P)*KBUFB); }             \
      oA0 = __builtin_amdgcn_mfma_f32_32x32x16_bf16(puA.v, vf0, oA0, 0,0,0);   \
      oA1 = __builtin_amdgcn_mfma_f32_32x32x16_bf16(puA.v, vf1, oA1, 0,0,0);   \
      oB0 = __builtin_amdgcn_mfma_f32_32x32x16_bf16(puB.v, vf0, oB0, 0,0,0);   \
      oB1 = __builtin_amdgcn_mfma_f32_32x32x16_bf16(puB.v, vf1, oB1, 0,0,0);   \
    }                                                                          \
    __builtin_amdgcn_s_setprio(0);                                             \
    __syncthreads();                                                           \
  }

  for (int t2=0; t2<NT/2; ++t2) {
    ATTN_TILE(0, 2*t2);
    ATTN_TILE(1, 2*t2+1);
  }
#undef ATTN_TILE
#undef MAKE_PU

  // combine hi-halves of the rowsum, then one reciprocal per q-half per lane
  lpA += __shfl_xor(lpA, 32);
  lpB += __shfl_xor(lpB, 32);
  const float qs = q_scale[h];
  const float ivA_lane = qs / lpA;   // valid for q = lane&31
  const float ivB_lane = qs / lpB;
#pragma unroll
  for (int r=0;r<16;r++) {
    const int qi = (r&3) + 8*(r>>2) + hi*4;
    {
      const float iv = __shfl(ivA_lane, qi);
      bf16* op = aout + (size_t)(b*SEQ + q0 + qi)*DM + h*64 + l31;
      op[0]  = (bf16)(oA0[r]*iv);
      op[32] = (bf16)(oA1[r]*iv);
    }
    {
      const float iv = __shfl(ivB_lane, qi);
      bf16* op = aout + (size_t)(b*SEQ + q0 + 32 + qi)*DM + h*64 + l31;
      op[0]  = (bf16)(oB0[r]*iv);
      op[32] = (bf16)(oB1[r]*iv);
    }
  }
}

// ---------------- launch ----------------
extern "C" void kernel_launch(void* const* d_in, const int* in_sizes, int n_in,
                              void* d_out, int out_size, void* d_ws, size_t ws_size,
                              hipStream_t stream) {
  (void)in_sizes; (void)n_in; (void)out_size; (void)ws_size;
  const float* x  = (const float*)d_in[0];
  const float* wq = (const float*)d_in[1];
  const float* bq = (const float*)d_in[2];
  const float* wk = (const float*)d_in[3];
  const float* bk = (const float*)d_in[4];
  const float* wv = (const float*)d_in[5];
  const float* bv = (const float*)d_in[6];
  const float* wo = (const float*)d_in[7];
  const float* bo = (const float*)d_in[8];
  const float* temp = (const float*)d_in[9];
  const float* qsc  = (const float*)d_in[10];

  char* ws = (char*)d_ws;
  bf16* xb    = (bf16*)ws; ws += (size_t)MTOK*DM*2;
  bf16* wqkvb = (bf16*)ws; ws += (size_t)NE*DM*2;
  bf16* wob   = (bf16*)ws; ws += (size_t)DM*DM*2;
  float* bqkv = (float*)ws; ws += (size_t)NE*4;
  bf16* qkv   = (bf16*)ws; ws += (size_t)MTOK*NE*2;
  bf16* vt    = (bf16*)ws; ws += (size_t)NB*NHEADS*DHEAD*SEQ*2;
  bf16* aout  = (bf16*)ws; ws += (size_t)MTOK*DM*2;

  convert_kernel<<<dim3(2048), dim3(256), 0, stream>>>(x, wq, wk, wv, wo, bq, bk, bv,
                                                       xb, wqkvb, wob, bqkv);
  gemm_deep<0><<<dim3(MTOK/128, NE/128), dim3(256), 0, stream>>>(xb, wqkvb, bqkv, qkv,
                                                                 MTOK, NE, DM);
  transpose_v<<<dim3(SEQ/64, NB*NHEADS), dim3(256), 0, stream>>>(qkv, vt);
  attn_kernel<<<dim3(512), dim3(256), 0, stream>>>(qkv, vt, aout, temp, qsc);
  gemm_deep<1><<<dim3(MTOK/128, DM/128), dim3(256), 0, stream>>>(aout, wob, bo, d_out,
                                                                 MTOK, DM, DM);
}

// Round 21
// 175.912 us; speedup vs baseline: 3.6402x; 1.0005x over previous
//
#include <hip/hip_runtime.h>
#include <hip/hip_bf16.h>
#include <stdint.h>

typedef __bf16 bf16;
typedef __bf16 bf16x8 __attribute__((ext_vector_type(8)));
typedef __bf16 bf16x4 __attribute__((ext_vector_type(4)));
typedef float f32x4 __attribute__((ext_vector_type(4)));
typedef float f32x16 __attribute__((ext_vector_type(16)));

#define NB 4
#define SEQ 2048
#define DM 1024
#define NHEADS 16
#define DHEAD 64
#define MTOK (NB*SEQ)      /* 8192 */
#define NE 3072            /* 3*DM */

__device__ __forceinline__ void gl_lds16(const bf16* g, bf16* l) {
  __builtin_amdgcn_global_load_lds(
      (const __attribute__((address_space(1))) void*)g,
      (__attribute__((address_space(3))) void*)l, 16, 0, 0);
}

__device__ __forceinline__ f32x16 zero16() {
  f32x16 z;
#pragma unroll
  for (int i=0;i<16;i++) z[i]=0.f;
  return z;
}

// ---------------- convert inputs to bf16 ----------------
__global__ __launch_bounds__(256) void convert_kernel(
    const float* __restrict__ x,
    const float* __restrict__ wq, const float* __restrict__ wk,
    const float* __restrict__ wv, const float* __restrict__ wo,
    const float* __restrict__ bq, const float* __restrict__ bk,
    const float* __restrict__ bv,
    bf16* __restrict__ xb, bf16* __restrict__ wqkvb,
    bf16* __restrict__ wob, float* __restrict__ bqkv) {
  int tid = blockIdx.x*blockDim.x + threadIdx.x;
  int nt = gridDim.x*blockDim.x;
  const int NX4 = MTOK*DM/4;
  for (int i = tid; i < NX4; i += nt) {
    float4 v = ((const float4*)x)[i];
    ((bf16x4*)xb)[i] = bf16x4{(bf16)v.x,(bf16)v.y,(bf16)v.z,(bf16)v.w};
  }
  const int NW4 = DM*DM/4;
  for (int i = tid; i < NW4; i += nt) {
    float4 a = ((const float4*)wq)[i];
    ((bf16x4*)wqkvb)[i] = bf16x4{(bf16)a.x,(bf16)a.y,(bf16)a.z,(bf16)a.w};
    float4 b = ((const float4*)wk)[i];
    ((bf16x4*)wqkvb)[i+NW4] = bf16x4{(bf16)b.x,(bf16)b.y,(bf16)b.z,(bf16)b.w};
    float4 c = ((const float4*)wv)[i];
    ((bf16x4*)wqkvb)[i+2*NW4] = bf16x4{(bf16)c.x,(bf16)c.y,(bf16)c.z,(bf16)c.w};
    float4 d = ((const float4*)wo)[i];
    ((bf16x4*)wob)[i] = bf16x4{(bf16)d.x,(bf16)d.y,(bf16)d.z,(bf16)d.w};
  }
  for (int i = tid; i < DM; i += nt) {
    bqkv[i] = bq[i]; bqkv[i+DM] = bk[i]; bqkv[i+2*DM] = bv[i];
  }
}

// ---- GEMM: 128x128, BK=64, dbuf LDS, counted vmcnt(8), XOR-swizzled (R7 exact).
// OUT_MODE 0 additionally writes the transposed V copy (vt[b,h,d,s]) for
// columns >= 2048, fusing the old transpose_v kernel into the epilogue.
template<int OUT_MODE>
__global__ __launch_bounds__(256) void gemm_deep(
    const bf16* __restrict__ A, const bf16* __restrict__ Bm,
    const float* __restrict__ bias, void* __restrict__ Cout,
    bf16* __restrict__ vtout,
    int M, int N, int K) {
  __shared__ bf16 As[2][128*64];
  __shared__ bf16 Bs[2][128*64];
  const int bm = blockIdx.x, bn = blockIdx.y;
  const int thr = threadIdx.x;
  const int w = thr>>6, lane = thr&63;
  const int wr = w>>1, wc = w&1;
  const int l4 = lane>>4, lm = lane&15;
  f32x4 acc[4][4];
#pragma unroll
  for (int m=0;m<4;m++)
#pragma unroll
    for (int n=0;n<4;n++) acc[m][n] = f32x4{0.f,0.f,0.f,0.f};

  const bf16* Abase = A + (size_t)bm*128*K;
  const bf16* Bbase = Bm + (size_t)bn*128*K;

  const int srow = thr>>3;
  const int sch  = ((thr&7) ^ (srow&7)) * 8;
  const bf16* Ag = Abase + (size_t)srow*K + sch;
  const bf16* Bg = Bbase + (size_t)srow*K + sch;
  const int dbase = thr*8;

  const int nk = K>>6;

  int aoff[2][4], boff[2][4];
#pragma unroll
  for (int ks=0;ks<2;ks++) {
#pragma unroll
    for (int m=0;m<4;m++) {
      const int r = wr*64 + m*16 + lm;
      aoff[ks][m] = r*64 + ((((ks<<2)|l4) ^ (lm&7))*8);
    }
#pragma unroll
    for (int n=0;n<4;n++) {
      const int r = wc*64 + n*16 + lm;
      boff[ks][n] = r*64 + ((((ks<<2)|l4) ^ (lm&7))*8);
    }
  }

#pragma unroll
  for (int c=0;c<4;c++) {
    gl_lds16(Ag + (size_t)c*32*K, &As[0][c*2048 + dbase]);
    gl_lds16(Bg + (size_t)c*32*K, &Bs[0][c*2048 + dbase]);
  }

  for (int kt=0; kt<nk; ++kt) {
    const int p = kt&1;
    const int st = (kt+1 < nk) ? kt+1 : 0;
    const size_t ko = (size_t)st*64;
#pragma unroll
    for (int c=0;c<4;c++) {
      gl_lds16(Ag + ko + (size_t)c*32*K, &As[p^1][c*2048 + dbase]);
      gl_lds16(Bg + ko + (size_t)c*32*K, &Bs[p^1][c*2048 + dbase]);
    }
    asm volatile("s_waitcnt vmcnt(8)" ::: "memory");
    __builtin_amdgcn_s_barrier();
    __builtin_amdgcn_sched_barrier(0);

    const bf16* Ac = As[p];
    const bf16* Bc = Bs[p];
    __builtin_amdgcn_s_setprio(1);
#pragma unroll
    for (int ks=0;ks<2;ks++) {
      bf16x8 af[4], bfr[4];
#pragma unroll
      for (int m=0;m<4;m++) af[m] = *(const bf16x8*)&Ac[aoff[ks][m]];
#pragma unroll
      for (int n=0;n<4;n++) bfr[n] = *(const bf16x8*)&Bc[boff[ks][n]];
#pragma unroll
      for (int m=0;m<4;m++)
#pragma unroll
        for (int n=0;n<4;n++)
          acc[m][n] = __builtin_amdgcn_mfma_f32_16x16x32_bf16(af[m], bfr[n], acc[m][n], 0, 0, 0);
    }
    __builtin_amdgcn_s_setprio(0);
    __builtin_amdgcn_s_barrier();
    __builtin_amdgcn_sched_barrier(0);
  }

  const int rbase = bm*128 + wr*64 + l4*4;
  const int cbase = bn*128 + wc*64;
#pragma unroll
  for (int n=0;n<4;n++) {
    const int col = cbase + n*16 + lm;
    const float bv = bias[col];
#pragma unroll
    for (int m=0;m<4;m++) {
      bf16 tv[4];
#pragma unroll
      for (int j=0;j<4;j++) {
        const int row = rbase + m*16 + j;
        const float v = acc[m][n][j] + bv;
        if (OUT_MODE == 0) {
          ((bf16*)Cout)[(size_t)row*N + col] = (bf16)v;
          tv[j] = (bf16)v;
        } else {
          ((float*)Cout)[(size_t)row*N + col] = v;
        }
      }
      if (OUT_MODE == 0 && col >= 2*DM) {
        // transposed V copy: vt[b][h][d][s] (4 consecutive s -> one 8B store)
        const int hd = col - 2*DM;            // h*64 + d
        const int row0 = rbase + m*16;        // multiple of 4
        const int b_ = row0 >> 11, s_ = row0 & 2047;
        bf16* vp = vtout + ((size_t)((b_<<4) + (hd>>6))*64 + (hd&63))*SEQ + s_;
        *(bf16x4*)vp = bf16x4{tv[0], tv[1], tv[2], tv[3]};
      }
    }
  }
}

// ---------------- flash attention: 4 waves x 64 q-rows (2 q-halves/wave) ----
// grid: 512 blocks (1-D, XCD-chunked: xcd = flat&7 owns a complete bh-octet so
// the 8 q-blocks sharing one (b,h)'s K/V co-locate on one XCD -> K/V L2-local).
// Main loop = R15 exact bits.
__global__ __launch_bounds__(256, 2) void attn_kernel(
    const bf16* __restrict__ qkv, const bf16* __restrict__ vt,
    bf16* __restrict__ aout,
    const float* __restrict__ temperature, const float* __restrict__ q_scale) {
  __shared__ bf16 smem[4][64*64];   // [K0][K1][V0][V1], rows 128B, XOR-swizzled 16B chunks
  const int flat = blockIdx.x;              // 0..511
  const int xcd = flat & 7, local = flat >> 3;
  const int bh = xcd*8 + (local>>3);        // 8 bh per XCD
  const int qb = local & 7;                 // q-block within bh
  const int b = bh>>4, h = bh&15;
  const int thr = threadIdx.x;
  const int w = thr>>6, lane = thr&63;
  const int l31 = lane&31, hi = lane>>5;
  const float sc2 = 1.4426950408889634f / (8.0f * temperature[0]);
  const int q0 = qb*256 + w*64;
  const int NT = SEQ/64;
#define KBUFB 8192        /* bytes per buffer */
#define VOFFB 16384       /* V region byte offset */

  // Q fragments for both q-halves, pre-scaled by sc2
  bf16x8 qfA[4], qfB[4];
  {
    const bf16* qpA = qkv + (size_t)(b*SEQ + q0 + l31)*NE + h*64 + hi*8;
    const bf16* qpB = qpA + (size_t)32*NE;
#pragma unroll
    for (int s=0;s<4;s++) {
      bf16x8 qa = *(const bf16x8*)(qpA + s*16);
      bf16x8 qb_ = *(const bf16x8*)(qpB + s*16);
#pragma unroll
      for (int j=0;j<8;j++) {
        qfA[s][j] = (bf16)((float)qa[j] * sc2);
        qfB[s][j] = (bf16)((float)qb_[j] * sc2);
      }
    }
  }

  f32x16 oA0 = zero16(), oA1 = zero16();
  f32x16 oB0 = zero16(), oB1 = zero16();
  float lpA = 0.f, lpB = 0.f;     // lane-local rowsum for q = lane&31 (this hi-half's k)

  const bf16* Kbase = qkv + (size_t)b*SEQ*NE + DM + h*64;
  const bf16* Vbase = vt + (size_t)bh*64*SEQ;

  // staging: thread -> row sr (0..63), chunk scb (0..3); swizzle chunk^=(row&7)
  const int sr = thr>>2, scb = thr&3;
  const int wb0 = sr*128 + (((scb*2+0) ^ (sr&7))<<4);
  const int wb1 = sr*128 + (((scb*2+1) ^ (sr&7))<<4);
  const int rsw = l31&7;

  // precomputed fragment read addresses; buffer/V region via imm offsets
  const char* kr0[4];
  const char* kr1[4];
#pragma unroll
  for (int s=0;s<4;s++) {
    const int slot = s*2 + hi;
    kr0[s] = (const char*)smem + l31*128      + ((slot ^ rsw)<<4);
    kr1[s] = (const char*)smem + (32+l31)*128 + ((slot ^ rsw)<<4);
  }

  const bf16* kgb = Kbase + (size_t)sr*NE + scb*16;
  const bf16* vgb = Vbase + (size_t)sr*SEQ + scb*16;

  bf16x8 ka, kb, va, vb;
  ka = *(const bf16x8*)(kgb);
  kb = *(const bf16x8*)(kgb + 8);
  va = *(const bf16x8*)(vgb);
  vb = *(const bf16x8*)(vgb + 8);
  *(bf16x8*)((char*)smem + wb0)         = ka;
  *(bf16x8*)((char*)smem + wb1)         = kb;
  *(bf16x8*)((char*)smem + VOFFB + wb0) = va;
  *(bf16x8*)((char*)smem + VOFFB + wb1) = vb;
  kgb += (size_t)64*NE; vgb += 64;
  ka = *(const bf16x8*)(kgb);
  kb = *(const bf16x8*)(kgb + 8);
  va = *(const bf16x8*)(vgb);
  vb = *(const bf16x8*)(vgb + 8);
  kgb += (size_t)64*NE; vgb += 64;
  __syncthreads();

#define MAKE_PU(PU, S0, S1, KS)                                                \
  { float e0,e1,e2,e3,e4,e5,e6,e7;                                             \
    if ((KS)==0)      { e0=S0[0]; e1=S0[1]; e2=S0[2]; e3=S0[3];                \
                        e4=S0[4]; e5=S0[5]; e6=S0[6]; e7=S0[7]; }              \
    else if ((KS)==1) { e0=S0[8]; e1=S0[9]; e2=S0[10];e3=S0[11];               \
                        e4=S0[12];e5=S0[13];e6=S0[14];e7=S0[15]; }             \
    else if ((KS)==2) { e0=S1[0]; e1=S1[1]; e2=S1[2]; e3=S1[3];                \
                        e4=S1[4]; e5=S1[5]; e6=S1[6]; e7=S1[7]; }              \
    else              { e0=S1[8]; e1=S1[9]; e2=S1[10];e3=S1[11];               \
                        e4=S1[12];e5=S1[13];e6=S1[14];e7=S1[15]; }             \
    unsigned a0,a1,b0,b1;                                                      \
    asm("v_cvt_pk_bf16_f32 %0, %1, %2" : "=v"(a0) : "v"(e0), "v"(e1));         \
    asm("v_cvt_pk_bf16_f32 %0, %1, %2" : "=v"(a1) : "v"(e2), "v"(e3));         \
    asm("v_cvt_pk_bf16_f32 %0, %1, %2" : "=v"(b0) : "v"(e4), "v"(e5));         \
    asm("v_cvt_pk_bf16_f32 %0, %1, %2" : "=v"(b1) : "v"(e6), "v"(e7));         \
    asm("v_permlane32_swap_b32 %0, %1" : "+v"(a0), "+v"(b0));                  \
    asm("v_permlane32_swap_b32 %0, %1" : "+v"(a1), "+v"(b1));                  \
    PU.u[0]=a0; PU.u[1]=a1; PU.u[2]=b0; PU.u[3]=b1; }

#define ATTN_TILE(P, T)                                                        \
  {                                                                            \
    const int t_ = (T);                                                        \
    if (t_ < NT-1) {                                                           \
      *(bf16x8*)((char*)smem + ((P)^1)*KBUFB + wb0)         = ka;              \
      *(bf16x8*)((char*)smem + ((P)^1)*KBUFB + wb1)         = kb;              \
      *(bf16x8*)((char*)smem + VOFFB + ((P)^1)*KBUFB + wb0) = va;              \
      *(bf16x8*)((char*)smem + VOFFB + ((P)^1)*KBUFB + wb1) = vb;              \
      if (t_ < NT-2) {                                                         \
        ka = *(const bf16x8*)(kgb);                                            \
        kb = *(const bf16x8*)(kgb + 8);                                        \
        va = *(const bf16x8*)(vgb);                                            \
        vb = *(const bf16x8*)(vgb + 8);                                        \
        kgb += (size_t)64*NE; vgb += 64;                                       \
      }                                                                        \
    }                                                                          \
    f32x16 sA0 = zero16(), sA1 = zero16(), sB0 = zero16(), sB1 = zero16();     \
    __builtin_amdgcn_s_setprio(1);                                             \
    _Pragma("unroll")                                                          \
    for (int s=0;s<4;s++) {                                                    \
      bf16x8 kf0 = *(const bf16x8*)(kr0[s] + (P)*KBUFB);                       \
      bf16x8 kf1 = *(const bf16x8*)(kr1[s] + (P)*KBUFB);                       \
      sA0 = __builtin_amdgcn_mfma_f32_32x32x16_bf16(kf0, qfA[s], sA0, 0,0,0);  \
      sB0 = __builtin_amdgcn_mfma_f32_32x32x16_bf16(kf0, qfB[s], sB0, 0,0,0);  \
      sA1 = __builtin_amdgcn_mfma_f32_32x32x16_bf16(kf1, qfA[s], sA1, 0,0,0);  \
      sB1 = __builtin_amdgcn_mfma_f32_32x32x16_bf16(kf1, qfB[s], sB1, 0,0,0);  \
    }                                                                          \
    __builtin_amdgcn_s_setprio(0);                                             \
    _Pragma("unroll")                                                          \
    for (int r=0;r<16;r++) { sA0[r] = __builtin_amdgcn_exp2f(sA0[r]); lpA += sA0[r]; } \
    _Pragma("unroll")                                                          \
    for (int r=0;r<16;r++) { sA1[r] = __builtin_amdgcn_exp2f(sA1[r]); lpA += sA1[r]; } \
    _Pragma("unroll")                                                          \
    for (int r=0;r<16;r++) { sB0[r] = __builtin_amdgcn_exp2f(sB0[r]); lpB += sB0[r]; } \
    _Pragma("unroll")                                                          \
    for (int r=0;r<16;r++) { sB1[r] = __builtin_amdgcn_exp2f(sB1[r]); lpB += sB1[r]; } \
    __builtin_amdgcn_s_setprio(1);                                             \
    _Pragma("unroll")                                                          \
    for (int ks=0;ks<4;ks++) {                                                 \
      union { unsigned u[4]; bf16x8 v; } puA, puB;                             \
      MAKE_PU(puA, sA0, sA1, ks);                                              \
      MAKE_PU(puB, sB0, sB1, ks);                                              \
      bf16x8 vf0, vf1;                                                         \
      if (ks==0) { vf0 = *(const bf16x8*)(kr0[0] + VOFFB + (P)*KBUFB);         \
                   vf1 = *(const bf16x8*)(kr1[0] + VOFFB + (P)*KBUFB); }       \
      else if (ks==1) { vf0 = *(const bf16x8*)(kr0[1] + VOFFB + (P)*KBUFB);    \
                   vf1 = *(const bf16x8*)(kr1[1] + VOFFB + (P)*KBUFB); }       \
      else if (ks==2) { vf0 = *(const bf16x8*)(kr0[2] + VOFFB + (P)*KBUFB);    \
                   vf1 = *(const bf16x8*)(kr1[2] + VOFFB + (P)*KBUFB); }       \
      else { vf0 = *(const bf16x8*)(kr0[3] + VOFFB + (P)*KBUFB);               \
             vf1 = *(const bf16x8*)(kr1[3] + VOFFB + (P)*KBUFB); }             \
      oA0 = __builtin_amdgcn_mfma_f32_32x32x16_bf16(puA.v, vf0, oA0, 0,0,0);   \
      oA1 = __builtin_amdgcn_mfma_f32_32x32x16_bf16(puA.v, vf1, oA1, 0,0,0);   \
      oB0 = __builtin_amdgcn_mfma_f32_32x32x16_bf16(puB.v, vf0, oB0, 0,0,0);   \
      oB1 = __builtin_amdgcn_mfma_f32_32x32x16_bf16(puB.v, vf1, oB1, 0,0,0);   \
    }                                                                          \
    __builtin_amdgcn_s_setprio(0);                                             \
    __syncthreads();                                                           \
  }

  for (int t2=0; t2<NT/2; ++t2) {
    ATTN_TILE(0, 2*t2);
    ATTN_TILE(1, 2*t2+1);
  }
#undef ATTN_TILE
#undef MAKE_PU

  // combine hi-halves of the rowsum, then one reciprocal per q-half per lane
  lpA += __shfl_xor(lpA, 32);
  lpB += __shfl_xor(lpB, 32);
  const float qs = q_scale[h];
  const float ivA_lane = qs / lpA;   // valid for q = lane&31
  const float ivB_lane = qs / lpB;
#pragma unroll
  for (int r=0;r<16;r++) {
    const int qi = (r&3) + 8*(r>>2) + hi*4;
    {
      const float iv = __shfl(ivA_lane, qi);
      bf16* op = aout + (size_t)(b*SEQ + q0 + qi)*DM + h*64 + l31;
      op[0]  = (bf16)(oA0[r]*iv);
      op[32] = (bf16)(oA1[r]*iv);
    }
    {
      const float iv = __shfl(ivB_lane, qi);
      bf16* op = aout + (size_t)(b*SEQ + q0 + 32 + qi)*DM + h*64 + l31;
      op[0]  = (bf16)(oB0[r]*iv);
      op[32] = (bf16)(oB1[r]*iv);
    }
  }
}

// ---------------- launch ----------------
extern "C" void kernel_launch(void* const* d_in, const int* in_sizes, int n_in,
                              void* d_out, int out_size, void* d_ws, size_t ws_size,
                              hipStream_t stream) {
  (void)in_sizes; (void)n_in; (void)out_size; (void)ws_size;
  const float* x  = (const float*)d_in[0];
  const float* wq = (const float*)d_in[1];
  const float* bq = (const float*)d_in[2];
  const float* wk = (const float*)d_in[3];
  const float* bk = (const float*)d_in[4];
  const float* wv = (const float*)d_in[5];
  const float* bv = (const float*)d_in[6];
  const float* wo = (const float*)d_in[7];
  const float* bo = (const float*)d_in[8];
  const float* temp = (const float*)d_in[9];
  const float* qsc  = (const float*)d_in[10];

  char* ws = (char*)d_ws;
  bf16* xb    = (bf16*)ws; ws += (size_t)MTOK*DM*2;
  bf16* wqkvb = (bf16*)ws; ws += (size_t)NE*DM*2;
  bf16* wob   = (bf16*)ws; ws += (size_t)DM*DM*2;
  float* bqkv = (float*)ws; ws += (size_t)NE*4;
  bf16* qkv   = (bf16*)ws; ws += (size_t)MTOK*NE*2;
  bf16* vt    = (bf16*)ws; ws += (size_t)NB*NHEADS*DHEAD*SEQ*2;
  bf16* aout  = (bf16*)ws; ws += (size_t)MTOK*DM*2;

  convert_kernel<<<dim3(2048), dim3(256), 0, stream>>>(x, wq, wk, wv, wo, bq, bk, bv,
                                                       xb, wqkvb, wob, bqkv);
  gemm_deep<0><<<dim3(MTOK/128, NE/128), dim3(256), 0, stream>>>(xb, wqkvb, bqkv, qkv,
                                                                 vt, MTOK, NE, DM);
  attn_kernel<<<dim3(512), dim3(256), 0, stream>>>(qkv, vt, aout, temp, qsc);
  gemm_deep<1><<<dim3(MTOK/128, DM/128), dim3(256), 0, stream>>>(aout, wob, bo, d_out,
                                                                 nullptr, MTOK, DM, DM);
}

// Round 22
// 161.861 us; speedup vs baseline: 3.9562x; 1.0868x over previous
//
#include <hip/hip_runtime.h>
#include <hip/hip_bf16.h>
#include <stdint.h>

typedef __bf16 bf16;
typedef __bf16 bf16x8 __attribute__((ext_vector_type(8)));
typedef __bf16 bf16x4 __attribute__((ext_vector_type(4)));
typedef float f32x4 __attribute__((ext_vector_type(4)));
typedef float f32x16 __attribute__((ext_vector_type(16)));

#define NB 4
#define SEQ 2048
#define DM 1024
#define NHEADS 16
#define DHEAD 64
#define MTOK (NB*SEQ)      /* 8192 */
#define NE 3072            /* 3*DM */

__device__ __forceinline__ void gl_lds16(const bf16* g, bf16* l) {
  __builtin_amdgcn_global_load_lds(
      (const __attribute__((address_space(1))) void*)g,
      (__attribute__((address_space(3))) void*)l, 16, 0, 0);
}

__device__ __forceinline__ f32x16 zero16() {
  f32x16 z;
#pragma unroll
  for (int i=0;i<16;i++) z[i]=0.f;
  return z;
}

// ---------------- convert inputs to bf16 ----------------
__global__ __launch_bounds__(256) void convert_kernel(
    const float* __restrict__ x,
    const float* __restrict__ wq, const float* __restrict__ wk,
    const float* __restrict__ wv, const float* __restrict__ wo,
    const float* __restrict__ bq, const float* __restrict__ bk,
    const float* __restrict__ bv,
    bf16* __restrict__ xb, bf16* __restrict__ wqkvb,
    bf16* __restrict__ wob, float* __restrict__ bqkv) {
  int tid = blockIdx.x*blockDim.x + threadIdx.x;
  int nt = gridDim.x*blockDim.x;
  const int NX4 = MTOK*DM/4;
  for (int i = tid; i < NX4; i += nt) {
    float4 v = ((const float4*)x)[i];
    ((bf16x4*)xb)[i] = bf16x4{(bf16)v.x,(bf16)v.y,(bf16)v.z,(bf16)v.w};
  }
  const int NW4 = DM*DM/4;
  for (int i = tid; i < NW4; i += nt) {
    float4 a = ((const float4*)wq)[i];
    ((bf16x4*)wqkvb)[i] = bf16x4{(bf16)a.x,(bf16)a.y,(bf16)a.z,(bf16)a.w};
    float4 b = ((const float4*)wk)[i];
    ((bf16x4*)wqkvb)[i+NW4] = bf16x4{(bf16)b.x,(bf16)b.y,(bf16)b.z,(bf16)b.w};
    float4 c = ((const float4*)wv)[i];
    ((bf16x4*)wqkvb)[i+2*NW4] = bf16x4{(bf16)c.x,(bf16)c.y,(bf16)c.z,(bf16)c.w};
    float4 d = ((const float4*)wo)[i];
    ((bf16x4*)wob)[i] = bf16x4{(bf16)d.x,(bf16)d.y,(bf16)d.z,(bf16)d.w};
  }
  for (int i = tid; i < DM; i += nt) {
    bqkv[i] = bq[i]; bqkv[i+DM] = bk[i]; bqkv[i+2*DM] = bv[i];
  }
}

// ---- GEMM: 128x128, BK=64, dbuf LDS, counted vmcnt(8), XOR-swizzled (R7 core).
// OUT_MODE 0 fuses the V transpose: blocks with cbase >= 2048 route their C-tile
// through a padded LDS buffer (overlaid on As/Bs) and emit coalesced bf16x8
// stores along s into vt[b,h,d,s].
template<int OUT_MODE>
__global__ __launch_bounds__(256) void gemm_deep(
    const bf16* __restrict__ A, const bf16* __restrict__ Bm,
    const float* __restrict__ bias, void* __restrict__ Cout,
    bf16* __restrict__ vtout,
    int M, int N, int K) {
  __shared__ bf16 smbuf[4*128*64];   // 64 KB: As = [0,16384), Bs = [16384,32768)
  bf16* Asb = smbuf;                 // As[p] at p*8192
  bf16* Bsb = smbuf + 16384;         // Bs[p] at p*8192
  const int bm = blockIdx.x, bn = blockIdx.y;
  const int thr = threadIdx.x;
  const int w = thr>>6, lane = thr&63;
  const int wr = w>>1, wc = w&1;
  const int l4 = lane>>4, lm = lane&15;
  f32x4 acc[4][4];
#pragma unroll
  for (int m=0;m<4;m++)
#pragma unroll
    for (int n=0;n<4;n++) acc[m][n] = f32x4{0.f,0.f,0.f,0.f};

  const bf16* Abase = A + (size_t)bm*128*K;
  const bf16* Bbase = Bm + (size_t)bn*128*K;

  const int srow = thr>>3;
  const int sch  = ((thr&7) ^ (srow&7)) * 8;
  const bf16* Ag = Abase + (size_t)srow*K + sch;
  const bf16* Bg = Bbase + (size_t)srow*K + sch;
  const int dbase = thr*8;

  const int nk = K>>6;

  int aoff[2][4], boff[2][4];
#pragma unroll
  for (int ks=0;ks<2;ks++) {
#pragma unroll
    for (int m=0;m<4;m++) {
      const int r = wr*64 + m*16 + lm;
      aoff[ks][m] = r*64 + ((((ks<<2)|l4) ^ (lm&7))*8);
    }
#pragma unroll
    for (int n=0;n<4;n++) {
      const int r = wc*64 + n*16 + lm;
      boff[ks][n] = r*64 + ((((ks<<2)|l4) ^ (lm&7))*8);
    }
  }

#pragma unroll
  for (int c=0;c<4;c++) {
    gl_lds16(Ag + (size_t)c*32*K, &Asb[c*2048 + dbase]);
    gl_lds16(Bg + (size_t)c*32*K, &Bsb[c*2048 + dbase]);
  }

  for (int kt=0; kt<nk; ++kt) {
    const int p = kt&1;
    const int st = (kt+1 < nk) ? kt+1 : 0;
    const size_t ko = (size_t)st*64;
#pragma unroll
    for (int c=0;c<4;c++) {
      gl_lds16(Ag + ko + (size_t)c*32*K, &Asb[(p^1)*8192 + c*2048 + dbase]);
      gl_lds16(Bg + ko + (size_t)c*32*K, &Bsb[(p^1)*8192 + c*2048 + dbase]);
    }
    asm volatile("s_waitcnt vmcnt(8)" ::: "memory");
    __builtin_amdgcn_s_barrier();
    __builtin_amdgcn_sched_barrier(0);

    const bf16* Ac = Asb + p*8192;
    const bf16* Bc = Bsb + p*8192;
    __builtin_amdgcn_s_setprio(1);
#pragma unroll
    for (int ks=0;ks<2;ks++) {
      bf16x8 af[4], bfr[4];
#pragma unroll
      for (int m=0;m<4;m++) af[m] = *(const bf16x8*)&Ac[aoff[ks][m]];
#pragma unroll
      for (int n=0;n<4;n++) bfr[n] = *(const bf16x8*)&Bc[boff[ks][n]];
#pragma unroll
      for (int m=0;m<4;m++)
#pragma unroll
        for (int n=0;n<4;n++)
          acc[m][n] = __builtin_amdgcn_mfma_f32_16x16x32_bf16(af[m], bfr[n], acc[m][n], 0, 0, 0);
    }
    __builtin_amdgcn_s_setprio(0);
    __builtin_amdgcn_s_barrier();
    __builtin_amdgcn_sched_barrier(0);
  }

  const int rbase = bm*128 + wr*64 + l4*4;
  const int cbase = bn*128 + wc*64;
  const bool vblk = (OUT_MODE == 0) && (bn*128 >= 2*DM);

  if (vblk) {
    // drain in-flight dummy-stage LDS writes before reusing smbuf as tbuf
    asm volatile("s_waitcnt vmcnt(0)" ::: "memory");
    __syncthreads();
  }

#define TPAD 136
#pragma unroll
  for (int n=0;n<4;n++) {
    const int col = cbase + n*16 + lm;
    const float bv = bias[col];
#pragma unroll
    for (int m=0;m<4;m++) {
      bf16 tv[4];
#pragma unroll
      for (int j=0;j<4;j++) {
        const int row = rbase + m*16 + j;
        const float v = acc[m][n][j] + bv;
        if (OUT_MODE == 0) {
          ((bf16*)Cout)[(size_t)row*N + col] = (bf16)v;
          tv[j] = (bf16)v;
        } else {
          ((float*)Cout)[(size_t)row*N + col] = v;
        }
      }
      if (vblk) {
        const int col_local = wc*64 + n*16 + lm;          // 0..127
        const int s_local   = wr*64 + l4*4 + m*16;        // 0..124, mult of 4
        *(bf16x4*)&smbuf[col_local*TPAD + s_local] = bf16x4{tv[0], tv[1], tv[2], tv[3]};
      }
    }
  }

  if (vblk) {
    __syncthreads();
    const int hdbase = bn*128 - 2*DM;          // 0..1023, this block's first h*64+d
    const int b_ = bm >> 4;
    const int sbase = (bm & 15) * 128;
#pragma unroll
    for (int i=0;i<8;i++) {
      const int flat = i*256 + thr;            // 0..2047
      const int hd_local = flat >> 4;          // 0..127
      const int sc8 = flat & 15;               // 0..15
      const int hd = hdbase + hd_local;
      bf16x8 v = *(const bf16x8*)&smbuf[hd_local*TPAD + sc8*8];
      bf16* vp = vtout + ((size_t)((b_<<4) + (hd>>6))*64 + (hd&63))*SEQ + sbase + sc8*8;
      *(bf16x8*)vp = v;
    }
  }
#undef TPAD
}

// ---------------- flash attention: 4 waves x 64 q-rows (2 q-halves/wave) ----
// grid: 512 blocks (1-D, XCD-chunked). Main loop = R15 exact bits.
__global__ __launch_bounds__(256, 2) void attn_kernel(
    const bf16* __restrict__ qkv, const bf16* __restrict__ vt,
    bf16* __restrict__ aout,
    const float* __restrict__ temperature, const float* __restrict__ q_scale) {
  __shared__ bf16 smem[4][64*64];   // [K0][K1][V0][V1], rows 128B, XOR-swizzled 16B chunks
  const int flat = blockIdx.x;              // 0..511
  const int xcd = flat & 7, local = flat >> 3;
  const int bh = xcd*8 + (local>>3);        // 8 bh per XCD
  const int qb = local & 7;                 // q-block within bh
  const int b = bh>>4, h = bh&15;
  const int thr = threadIdx.x;
  const int w = thr>>6, lane = thr&63;
  const int l31 = lane&31, hi = lane>>5;
  const float sc2 = 1.4426950408889634f / (8.0f * temperature[0]);
  const int q0 = qb*256 + w*64;
  const int NT = SEQ/64;
#define KBUFB 8192        /* bytes per buffer */
#define VOFFB 16384       /* V region byte offset */

  // Q fragments for both q-halves, pre-scaled by sc2
  bf16x8 qfA[4], qfB[4];
  {
    const bf16* qpA = qkv + (size_t)(b*SEQ + q0 + l31)*NE + h*64 + hi*8;
    const bf16* qpB = qpA + (size_t)32*NE;
#pragma unroll
    for (int s=0;s<4;s++) {
      bf16x8 qa = *(const bf16x8*)(qpA + s*16);
      bf16x8 qb_ = *(const bf16x8*)(qpB + s*16);
#pragma unroll
      for (int j=0;j<8;j++) {
        qfA[s][j] = (bf16)((float)qa[j] * sc2);
        qfB[s][j] = (bf16)((float)qb_[j] * sc2);
      }
    }
  }

  f32x16 oA0 = zero16(), oA1 = zero16();
  f32x16 oB0 = zero16(), oB1 = zero16();
  float lpA = 0.f, lpB = 0.f;     // lane-local rowsum for q = lane&31 (this hi-half's k)

  const bf16* Kbase = qkv + (size_t)b*SEQ*NE + DM + h*64;
  const bf16* Vbase = vt + (size_t)bh*64*SEQ;

  // staging: thread -> row sr (0..63), chunk scb (0..3); swizzle chunk^=(row&7)
  const int sr = thr>>2, scb = thr&3;
  const int wb0 = sr*128 + (((scb*2+0) ^ (sr&7))<<4);
  const int wb1 = sr*128 + (((scb*2+1) ^ (sr&7))<<4);
  const int rsw = l31&7;

  // precomputed fragment read addresses; buffer/V region via imm offsets
  const char* kr0[4];
  const char* kr1[4];
#pragma unroll
  for (int s=0;s<4;s++) {
    const int slot = s*2 + hi;
    kr0[s] = (const char*)smem + l31*128      + ((slot ^ rsw)<<4);
    kr1[s] = (const char*)smem + (32+l31)*128 + ((slot ^ rsw)<<4);
  }

  const bf16* kgb = Kbase + (size_t)sr*NE + scb*16;
  const bf16* vgb = Vbase + (size_t)sr*SEQ + scb*16;

  bf16x8 ka, kb, va, vb;
  ka = *(const bf16x8*)(kgb);
  kb = *(const bf16x8*)(kgb + 8);
  va = *(const bf16x8*)(vgb);
  vb = *(const bf16x8*)(vgb + 8);
  *(bf16x8*)((char*)smem + wb0)         = ka;
  *(bf16x8*)((char*)smem + wb1)         = kb;
  *(bf16x8*)((char*)smem + VOFFB + wb0) = va;
  *(bf16x8*)((char*)smem + VOFFB + wb1) = vb;
  kgb += (size_t)64*NE; vgb += 64;
  ka = *(const bf16x8*)(kgb);
  kb = *(const bf16x8*)(kgb + 8);
  va = *(const bf16x8*)(vgb);
  vb = *(const bf16x8*)(vgb + 8);
  kgb += (size_t)64*NE; vgb += 64;
  __syncthreads();

#define MAKE_PU(PU, S0, S1, KS)                                                \
  { float e0,e1,e2,e3,e4,e5,e6,e7;                                             \
    if ((KS)==0)      { e0=S0[0]; e1=S0[1]; e2=S0[2]; e3=S0[3];                \
                        e4=S0[4]; e5=S0[5]; e6=S0[6]; e7=S0[7]; }              \
    else if ((KS)==1) { e0=S0[8]; e1=S0[9]; e2=S0[10];e3=S0[11];               \
                        e4=S0[12];e5=S0[13];e6=S0[14];e7=S0[15]; }             \
    else if ((KS)==2) { e0=S1[0]; e1=S1[1]; e2=S1[2]; e3=S1[3];                \
                        e4=S1[4]; e5=S1[5]; e6=S1[6]; e7=S1[7]; }              \
    else              { e0=S1[8]; e1=S1[9]; e2=S1[10];e3=S1[11];               \
                        e4=S1[12];e5=S1[13];e6=S1[14];e7=S1[15]; }             \
    unsigned a0,a1,b0,b1;                                                      \
    asm("v_cvt_pk_bf16_f32 %0, %1, %2" : "=v"(a0) : "v"(e0), "v"(e1));         \
    asm("v_cvt_pk_bf16_f32 %0, %1, %2" : "=v"(a1) : "v"(e2), "v"(e3));         \
    asm("v_cvt_pk_bf16_f32 %0, %1, %2" : "=v"(b0) : "v"(e4), "v"(e5));         \
    asm("v_cvt_pk_bf16_f32 %0, %1, %2" : "=v"(b1) : "v"(e6), "v"(e7));         \
    asm("v_permlane32_swap_b32 %0, %1" : "+v"(a0), "+v"(b0));                  \
    asm("v_permlane32_swap_b32 %0, %1" : "+v"(a1), "+v"(b1));                  \
    PU.u[0]=a0; PU.u[1]=a1; PU.u[2]=b0; PU.u[3]=b1; }

#define ATTN_TILE(P, T)                                                        \
  {                                                                            \
    const int t_ = (T);                                                        \
    if (t_ < NT-1) {                                                           \
      *(bf16x8*)((char*)smem + ((P)^1)*KBUFB + wb0)         = ka;              \
      *(bf16x8*)((char*)smem + ((P)^1)*KBUFB + wb1)         = kb;              \
      *(bf16x8*)((char*)smem + VOFFB + ((P)^1)*KBUFB + wb0) = va;              \
      *(bf16x8*)((char*)smem + VOFFB + ((P)^1)*KBUFB + wb1) = vb;              \
      if (t_ < NT-2) {                                                         \
        ka = *(const bf16x8*)(kgb);                                            \
        kb = *(const bf16x8*)(kgb + 8);                                        \
        va = *(const bf16x8*)(vgb);                                            \
        vb = *(const bf16x8*)(vgb + 8);                                        \
        kgb += (size_t)64*NE; vgb += 64;                                       \
      }                                                                        \
    }                                                                          \
    f32x16 sA0 = zero16(), sA1 = zero16(), sB0 = zero16(), sB1 = zero16();     \
    __builtin_amdgcn_s_setprio(1);                                             \
    _Pragma("unroll")                                                          \
    for (int s=0;s<4;s++) {                                                    \
      bf16x8 kf0 = *(const bf16x8*)(kr0[s] + (P)*KBUFB);                       \
      bf16x8 kf1 = *(const bf16x8*)(kr1[s] + (P)*KBUFB);                       \
      sA0 = __builtin_amdgcn_mfma_f32_32x32x16_bf16(kf0, qfA[s], sA0, 0,0,0);  \
      sB0 = __builtin_amdgcn_mfma_f32_32x32x16_bf16(kf0, qfB[s], sB0, 0,0,0);  \
      sA1 = __builtin_amdgcn_mfma_f32_32x32x16_bf16(kf1, qfA[s], sA1, 0,0,0);  \
      sB1 = __builtin_amdgcn_mfma_f32_32x32x16_bf16(kf1, qfB[s], sB1, 0,0,0);  \
    }                                                                          \
    __builtin_amdgcn_s_setprio(0);                                             \
    _Pragma("unroll")                                                          \
    for (int r=0;r<16;r++) { sA0[r] = __builtin_amdgcn_exp2f(sA0[r]); lpA += sA0[r]; } \
    _Pragma("unroll")                                                          \
    for (int r=0;r<16;r++) { sA1[r] = __builtin_amdgcn_exp2f(sA1[r]); lpA += sA1[r]; } \
    _Pragma("unroll")                                                          \
    for (int r=0;r<16;r++) { sB0[r] = __builtin_amdgcn_exp2f(sB0[r]); lpB += sB0[r]; } \
    _Pragma("unroll")                                                          \
    for (int r=0;r<16;r++) { sB1[r] = __builtin_amdgcn_exp2f(sB1[r]); lpB += sB1[r]; } \
    __builtin_amdgcn_s_setprio(1);                                             \
    _Pragma("unroll")                                                          \
    for (int ks=0;ks<4;ks++) {                                                 \
      union { unsigned u[4]; bf16x8 v; } puA, puB;                             \
      MAKE_PU(puA, sA0, sA1, ks);                                              \
      MAKE_PU(puB, sB0, sB1, ks);                                              \
      bf16x8 vf0, vf1;                                                         \
      if (ks==0) { vf0 = *(const bf16x8*)(kr0[0] + VOFFB + (P)*KBUFB);         \
                   vf1 = *(const bf16x8*)(kr1[0] + VOFFB + (P)*KBUFB); }       \
      else if (ks==1) { vf0 = *(const bf16x8*)(kr0[1] + VOFFB + (P)*KBUFB);    \
                   vf1 = *(const bf16x8*)(kr1[1] + VOFFB + (P)*KBUFB); }       \
      else if (ks==2) { vf0 = *(const bf16x8*)(kr0[2] + VOFFB + (P)*KBUFB);    \
                   vf1 = *(const bf16x8*)(kr1[2] + VOFFB + (P)*KBUFB); }       \
      else { vf0 = *(const bf16x8*)(kr0[3] + VOFFB + (P)*KBUFB);               \
             vf1 = *(const bf16x8*)(kr1[3] + VOFFB + (P)*KBUFB); }             \
      oA0 = __builtin_amdgcn_mfma_f32_32x32x16_bf16(puA.v, vf0, oA0, 0,0,0);   \
      oA1 = __builtin_amdgcn_mfma_f32_32x32x16_bf16(puA.v, vf1, oA1, 0,0,0);   \
      oB0 = __builtin_amdgcn_mfma_f32_32x32x16_bf16(puB.v, vf0, oB0, 0,0,0);   \
      oB1 = __builtin_amdgcn_mfma_f32_32x32x16_bf16(puB.v, vf1, oB1, 0,0,0);   \
    }                                                                          \
    __builtin_amdgcn_s_setprio(0);                                             \
    __syncthreads();                                                           \
  }

  for (int t2=0; t2<NT/2; ++t2) {
    ATTN_TILE(0, 2*t2);
    ATTN_TILE(1, 2*t2+1);
  }
#undef ATTN_TILE
#undef MAKE_PU

  // combine hi-halves of the rowsum, then one reciprocal per q-half per lane
  lpA += __shfl_xor(lpA, 32);
  lpB += __shfl_xor(lpB, 32);
  const float qs = q_scale[h];
  const float ivA_lane = qs / lpA;   // valid for q = lane&31
  const float ivB_lane = qs / lpB;
#pragma unroll
  for (int r=0;r<16;r++) {
    const int qi = (r&3) + 8*(r>>2) + hi*4;
    {
      const float iv = __shfl(ivA_lane, qi);
      bf16* op = aout + (size_t)(b*SEQ + q0 + qi)*DM + h*64 + l31;
      op[0]  = (bf16)(oA0[r]*iv);
      op[32] = (bf16)(oA1[r]*iv);
    }
    {
      const float iv = __shfl(ivB_lane, qi);
      bf16* op = aout + (size_t)(b*SEQ + q0 + 32 + qi)*DM + h*64 + l31;
      op[0]  = (bf16)(oB0[r]*iv);
      op[32] = (bf16)(oB1[r]*iv);
    }
  }
}

// ---------------- launch ----------------
extern "C" void kernel_launch(void* const* d_in, const int* in_sizes, int n_in,
                              void* d_out, int out_size, void* d_ws, size_t ws_size,
                              hipStream_t stream) {
  (void)in_sizes; (void)n_in; (void)out_size; (void)ws_size;
  const float* x  = (const float*)d_in[0];
  const float* wq = (const float*)d_in[1];
  const float* bq = (const float*)d_in[2];
  const float* wk = (const float*)d_in[3];
  const float* bk = (const float*)d_in[4];
  const float* wv = (const float*)d_in[5];
  const float* bv = (const float*)d_in[6];
  const float* wo = (const float*)d_in[7];
  const float* bo = (const float*)d_in[8];
  const float* temp = (const float*)d_in[9];
  const float* qsc  = (const float*)d_in[10];

  char* ws = (char*)d_ws;
  bf16* xb    = (bf16*)ws; ws += (size_t)MTOK*DM*2;
  bf16* wqkvb = (bf16*)ws; ws += (size_t)NE*DM*2;
  bf16* wob   = (bf16*)ws; ws += (size_t)DM*DM*2;
  float* bqkv = (float*)ws; ws += (size_t)NE*4;
  bf16* qkv   = (bf16*)ws; ws += (size_t)MTOK*NE*2;
  bf16* vt    = (bf16*)ws; ws += (size_t)NB*NHEADS*DHEAD*SEQ*2;
  bf16* aout  = (bf16*)ws; ws += (size_t)MTOK*DM*2;

  convert_kernel<<<dim3(2048), dim3(256), 0, stream>>>(x, wq, wk, wv, wo, bq, bk, bv,
                                                       xb, wqkvb, wob, bqkv);
  gemm_deep<0><<<dim3(MTOK/128, NE/128), dim3(256), 0, stream>>>(xb, wqkvb, bqkv, qkv,
                                                                 vt, MTOK, NE, DM);
  attn_kernel<<<dim3(512), dim3(256), 0, stream>>>(qkv, vt, aout, temp, qsc);
  gemm_deep<1><<<dim3(MTOK/128, DM/128), dim3(256), 0, stream>>>(aout, wob, bo, d_out,
                                                                 nullptr, MTOK, DM, DM);
}